// Round 5
// baseline (4151.751 us; speedup 1.0000x reference)
//
#include <hip/hip_runtime.h>
#include <cstdint>
#include <cstddef>

// ---------------------------------------------------------------------------
// B=16 V=30522 D=512 H=8 DH=64 FF=2048 NC=4 NF=30 NN=34 FL=64 HL=32 L=2
// INPUT float tensors may be fp32 OR bf16 -- detected at runtime from ln1_g
// (all 1.0): fp32 -> first u32 == 0x3F800000 ; bf16 -> 0x3F803F80.
// OUTPUT: 65 FLOAT32 values = [loss, final_pred(16x4)]  (reference output
// dtype is float32; round-4 experiment proved the harness decodes fp32).
// ---------------------------------------------------------------------------

using u16 = unsigned short;

typedef __bf16 bf16x8 __attribute__((ext_vector_type(8)));
typedef float  floatx4 __attribute__((ext_vector_type(4)));

__device__ __forceinline__ float bf2f(u16 u) {
  return __uint_as_float(((unsigned)u) << 16);
}
__device__ __forceinline__ u16 f2bf(float f) {
  unsigned u = __float_as_uint(f);
  u += 0x7FFFu + ((u >> 16) & 1u);   // round-to-nearest-even
  return (u16)(u >> 16);
}
__device__ __forceinline__ float ldf(const void* p, size_t i, int isb) {
  return isb ? bf2f(((const u16*)p)[i]) : ((const float*)p)[i];
}

__device__ __forceinline__ float waveSum(float v) {
#pragma unroll
  for (int o = 32; o > 0; o >>= 1) v += __shfl_xor(v, o, 64);
  return v;
}
__device__ __forceinline__ float waveMax(float v) {
#pragma unroll
  for (int o = 32; o > 0; o >>= 1) v = fmaxf(v, __shfl_xor(v, o, 64));
  return v;
}
__device__ __forceinline__ float blockSum(float v, float* sh4) {
  v = waveSum(v);
  if ((threadIdx.x & 63) == 0) sh4[threadIdx.x >> 6] = v;
  __syncthreads();
  float r = sh4[0] + sh4[1] + sh4[2] + sh4[3];
  __syncthreads();
  return r;
}
__device__ __forceinline__ float blockMax(float v, float* sh4) {
  v = waveMax(v);
  if ((threadIdx.x & 63) == 0) sh4[threadIdx.x >> 6] = v;
  __syncthreads();
  float r = fmaxf(fmaxf(sh4[0], sh4[1]), fmaxf(sh4[2], sh4[3]));
  __syncthreads();
  return r;
}

// ---------------------------------------------------------------------------
__global__ void detect_kernel(const void* __restrict__ ln1g, int* __restrict__ flag) {
  unsigned u = *(const unsigned*)ln1g;
  *flag = (u == 0x3F800000u) ? 0 : 1;
}

// ---------------------------------------------------------------------------
// Transpose + ->bf16: src elements [eoff + k*N + n] -> dst[n*K + k].
// ---------------------------------------------------------------------------
__global__ __launch_bounds__(256) void transpose_kernel(const void* __restrict__ src,
                                                        u16* __restrict__ dst,
                                                        int K, int N, size_t eoff,
                                                        const int* __restrict__ F) {
  const int isb = *F;
  __shared__ u16 tile[32][33];
  int bx = blockIdx.x, by = blockIdx.y;
  int tx = threadIdx.x & 31, ty = threadIdx.x >> 5;
  for (int i = ty; i < 32; i += 8)
    tile[i][tx] = f2bf(ldf(src, eoff + (size_t)(by * 32 + i) * N + bx * 32 + tx, isb));
  __syncthreads();
  for (int i = ty; i < 32; i += 8)
    dst[(size_t)(bx * 32 + i) * K + by * 32 + tx] = tile[tx][i];
}

// ---------------------------------------------------------------------------
// Embedding + positional encoding. One block per token.
// ---------------------------------------------------------------------------
__global__ __launch_bounds__(256) void embed_kernel(const int* __restrict__ ids,
                                                    const void* __restrict__ emb,
                                                    u16* __restrict__ x, int L,
                                                    const int* __restrict__ F) {
  const int isb = *F;
  int tok = blockIdx.x;
  int pos = tok % L;
  int id = ids[tok];
  const float LOG1E4_OVER_D = 9.210340371976184f / 512.0f;
  for (int d = threadIdx.x; d < 512; d += 256) {
    float e = ldf(emb, (size_t)id * 512 + d, isb) * 22.62741699796952f;
    int i2 = d & ~1;
    float ang = (float)pos * expf(-(float)i2 * LOG1E4_OVER_D);
    float pe = (d & 1) ? cosf(ang) : sinf(ang);
    x[(size_t)tok * 512 + d] = f2bf(e + pe);
  }
}

// ---------------------------------------------------------------------------
// GEMM: C[M][N] = A[M][K] @ Bt[N][K]^T + bias[boff..]  (optional relu)
// bf16 in, fp32 MFMA accumulate, bf16 out. 128x128 tile, BK=64, 256 threads.
// ---------------------------------------------------------------------------
template <int RELU>
__global__ __launch_bounds__(256, 2) void gemm_bt(const u16* __restrict__ A,
                                                  const u16* __restrict__ Bt,
                                                  const void* __restrict__ bias,
                                                  u16* __restrict__ C,
                                                  int M, int N, int K, size_t boff,
                                                  const int* __restrict__ F) {
  const int isb = *F;
  __shared__ __align__(16) u16 As[128 * 64];
  __shared__ __align__(16) u16 Bs[128 * 64];
  const int tid = threadIdx.x;
  const int lane = tid & 63;
  const int wave = tid >> 6;
  const int wm = wave >> 1, wn = wave & 1;
  const int l15 = lane & 15, quad = lane >> 4;
  const int bm = blockIdx.y, bn = blockIdx.x;

  floatx4 acc[4][4];
#pragma unroll
  for (int i = 0; i < 4; i++)
#pragma unroll
    for (int j = 0; j < 4; j++) acc[i][j] = (floatx4){0.f, 0.f, 0.f, 0.f};

  const u16* Abase = A + (size_t)bm * 128 * K;
  const u16* Bbase = Bt + (size_t)bn * 128 * K;

  for (int kt = 0; kt < K; kt += 64) {
#pragma unroll
    for (int i = 0; i < 4; i++) {
      int c = i * 256 + tid;
      int row = c >> 3, col = (c & 7) * 8;
      *(uint4*)&As[c * 8] = *(const uint4*)&Abase[(size_t)row * K + kt + col];
      *(uint4*)&Bs[c * 8] = *(const uint4*)&Bbase[(size_t)row * K + kt + col];
    }
    __syncthreads();
#pragma unroll
    for (int ks = 0; ks < 2; ks++) {
      bf16x8 af[4], bfr[4];
#pragma unroll
      for (int mi = 0; mi < 4; mi++)
        af[mi] = *(const bf16x8*)&As[(wm * 64 + mi * 16 + l15) * 64 + ks * 32 + quad * 8];
#pragma unroll
      for (int ni = 0; ni < 4; ni++)
        bfr[ni] = *(const bf16x8*)&Bs[(wn * 64 + ni * 16 + l15) * 64 + ks * 32 + quad * 8];
#pragma unroll
      for (int mi = 0; mi < 4; mi++)
#pragma unroll
        for (int ni = 0; ni < 4; ni++)
          acc[mi][ni] = __builtin_amdgcn_mfma_f32_16x16x32_bf16(af[mi], bfr[ni], acc[mi][ni], 0, 0, 0);
    }
    __syncthreads();
  }

#pragma unroll
  for (int ni = 0; ni < 4; ni++) {
    int gcol = bn * 128 + wn * 64 + ni * 16 + l15;
    float bv = ldf(bias, boff + gcol, isb);
#pragma unroll
    for (int mi = 0; mi < 4; mi++) {
#pragma unroll
      for (int r = 0; r < 4; r++) {
        int grow = bm * 128 + wm * 64 + mi * 16 + quad * 4 + r;
        float v = acc[mi][ni][r] + bv;
        if (RELU) v = fmaxf(v, 0.f);
        C[(size_t)grow * N + gcol] = f2bf(v);
      }
    }
  }
}

// ---------------------------------------------------------------------------
// Attention: one block per (seq, head).
// ---------------------------------------------------------------------------
__global__ __launch_bounds__(256) void attn_kernel(const u16* __restrict__ qkv,
                                                   u16* __restrict__ o, int L) {
  const int h = blockIdx.x & 7;
  const int s = blockIdx.x >> 3;
  __shared__ u16 Qs[64][68];
  __shared__ u16 Ks[64][68];
  __shared__ u16 Vs[64][68];
  __shared__ float Ss[64][65];
  const int tid = threadIdx.x;
  const int base = s * L;

  for (int idx = tid; idx < L * 64; idx += 256) {
    int t = idx >> 6, d = idx & 63;
    size_t g = (size_t)(base + t) * 1536 + h * 64 + d;
    Qs[t][d] = qkv[g];
    Ks[t][d] = qkv[g + 512];
    Vs[t][d] = qkv[g + 1024];
  }
  __syncthreads();

  for (int idx = tid; idx < L * L; idx += 256) {
    int i = idx / L, j = idx - i * L;
    float acc = 0.f;
#pragma unroll
    for (int d = 0; d < 64; d++) acc += bf2f(Qs[i][d]) * bf2f(Ks[j][d]);
    Ss[i][j] = acc * 0.125f;
  }
  __syncthreads();

  if (tid < L) {
    float mx = -3.4e38f;
    for (int j = 0; j < L; j++) mx = fmaxf(mx, Ss[tid][j]);
    float sum = 0.f;
    for (int j = 0; j < L; j++) { float e = expf(Ss[tid][j] - mx); Ss[tid][j] = e; sum += e; }
    float inv = 1.f / sum;
    for (int j = 0; j < L; j++) Ss[tid][j] *= inv;
  }
  __syncthreads();

  for (int idx = tid; idx < L * 64; idx += 256) {
    int t = idx >> 6, d = idx & 63;
    float acc = 0.f;
    for (int j = 0; j < L; j++) acc += Ss[t][j] * bf2f(Vs[j][d]);
    o[(size_t)(base + t) * 512 + h * 64 + d] = f2bf(acc);
  }
}

// ---------------------------------------------------------------------------
// x = LayerNorm(x + y) * g[eoff..] + b[eoff..]
// ---------------------------------------------------------------------------
__global__ __launch_bounds__(256) void add_ln_kernel(u16* __restrict__ x,
                                                     const u16* __restrict__ y,
                                                     const void* __restrict__ g,
                                                     const void* __restrict__ b,
                                                     size_t eoff,
                                                     const int* __restrict__ F) {
  const int isb = *F;
  const int row = blockIdx.x, tid = threadIdx.x;
  __shared__ float sh[4];
  size_t o0 = (size_t)row * 512 + tid;
  float v0 = bf2f(x[o0]) + bf2f(y[o0]);
  float v1 = bf2f(x[o0 + 256]) + bf2f(y[o0 + 256]);
  float mean = blockSum(v0 + v1, sh) * (1.f / 512.f);
  float d0 = v0 - mean, d1 = v1 - mean;
  float var = blockSum(d0 * d0 + d1 * d1, sh) * (1.f / 512.f);
  float rstd = rsqrtf(var + 1e-5f);
  x[o0]       = f2bf(d0 * rstd * ldf(g, eoff + tid, isb)       + ldf(b, eoff + tid, isb));
  x[o0 + 256] = f2bf(d1 * rstd * ldf(g, eoff + tid + 256, isb) + ldf(b, eoff + tid + 256, isb));
}

// ---------------------------------------------------------------------------
// Masked mean pool; mask elements at [moff + s*L + t].
// ---------------------------------------------------------------------------
__global__ __launch_bounds__(256) void pool_kernel(const u16* __restrict__ x,
                                                   const void* __restrict__ mask,
                                                   float* __restrict__ pooled, int L,
                                                   size_t moff,
                                                   const int* __restrict__ F) {
  const int isb = *F;
  const int s = blockIdx.x;
  float msum = 0.f;
  for (int t = 0; t < L; t++) msum += ldf(mask, moff + s * L + t, isb);
  float inv = 1.f / fmaxf(msum, 1e-9f);
  for (int d = threadIdx.x; d < 512; d += 256) {
    float acc = 0.f;
    for (int t = 0; t < L; t++)
      acc += bf2f(x[(size_t)(s * L + t) * 512 + d]) * ldf(mask, moff + s * L + t, isb);
    pooled[(size_t)s * 512 + d] = acc * inv;
  }
}

// ---------------------------------------------------------------------------
// Pairwise score
// ---------------------------------------------------------------------------
__global__ __launch_bounds__(64) void pair_score_kernel(const float* __restrict__ X,
                                                        const float* __restrict__ Y,
                                                        const void* __restrict__ Wv,
                                                        const void* __restrict__ bscal,
                                                        float* __restrict__ outp,
                                                        int NI, int NJ,
                                                        const int* __restrict__ F) {
  const int isb = *F;
  int gid = blockIdx.x;
  int j = gid % NJ;
  int t = gid / NJ;
  int i = t % NI;
  int b = t / NI;
  const float* xv = X + ((size_t)b * NI + i) * 512;
  const float* yv = Y + ((size_t)b * NJ + j) * 512;
  int l = threadIdx.x;
  float p = 0.f;
  for (int d = l; d < 512; d += 64) {
    float xi = xv[d], yj = yv[d];
    p += ldf(Wv, d, isb) * yj + ldf(Wv, 512 + d, isb) * xi +
         ldf(Wv, 1024 + d, isb) * fabsf(yj - xi) + ldf(Wv, 1536 + d, isb) * xi * yj;
  }
  p = waveSum(p);
  if (l == 0) outp[gid] = p + ldf(bscal, 0, isb);
}

__global__ __launch_bounds__(256) void aa_softmax_kernel(const float* __restrict__ aa,
                                                         float* __restrict__ aasm) {
  const int b = blockIdx.x;
  const float* src = aa + (size_t)b * 900;
  float* dst = aasm + (size_t)b * 900;
  __shared__ float sh[4];
  int tid = threadIdx.x;
  float mx = -3.4e38f;
  for (int i = tid; i < 900; i += 256) mx = fmaxf(mx, src[i]);
  mx = blockMax(mx, sh);
  float sum = 0.f;
  for (int i = tid; i < 900; i += 256) sum += expf(src[i] - mx);
  sum = blockSum(sum, sh);
  float inv = 1.f / sum;
  for (int i = tid; i < 900; i += 256) {
    int r = i / 30, c = i - r * 30;
    dst[i] = (r == c) ? 0.f : expf(src[i] - mx) * inv;
  }
}

__global__ __launch_bounds__(64) void qa_softmax_kernel(const float* __restrict__ qa,
                                                        float* __restrict__ sim) {
  int g = blockIdx.x;
  int l = threadIdx.x;
  float v = (l < 30) ? qa[(size_t)g * 30 + l] : -3.4e38f;
  float mx = waveMax(v);
  float e = (l < 30) ? expf(v - mx) : 0.f;
  float s = waveSum(e);
  if (l < 30) sim[(size_t)g * 30 + l] = e / s;
}

// ---------------------------------------------------------------------------
// Edge weights
// ---------------------------------------------------------------------------
__global__ __launch_bounds__(256) void edgew_kernel(const void* __restrict__ aaov,
                                                    const void* __restrict__ aasim_in,
                                                    const void* __restrict__ qaov,
                                                    const void* __restrict__ qq,
                                                    const float* __restrict__ aasm,
                                                    const float* __restrict__ sim,
                                                    const void* __restrict__ p1,
                                                    const void* __restrict__ p2,
                                                    const void* __restrict__ p3,
                                                    const void* __restrict__ p4,
                                                    float* __restrict__ Wout,
                                                    const int* __restrict__ F) {
  const int isb = *F;
  int e = blockIdx.x * 256 + threadIdx.x;
  if (e >= 16 * 1156) return;
  int b = e / 1156;
  int rem = e - b * 1156;
  int r = rem / 34, c = rem - r * 34;
  float aas;
  if (r >= 4 && c >= 4) aas = aasm[(size_t)b * 900 + (r - 4) * 30 + (c - 4)];
  else                  aas = ldf(aasim_in, e, isb);
  float qas = 0.f;
  if (r >= 4 && c < 4)      qas = sim[((size_t)b * 4 + c) * 30 + (r - 4)];
  else if (r < 4 && c >= 4) qas = sim[((size_t)b * 4 + r) * 30 + (c - 4)];
  float w = -ldf(p1, 0, isb) * ldf(aaov, e, isb) + ldf(p2, 0, isb) * aas +
            ldf(p3, 0, isb) * ldf(qaov, e, isb) + ldf(p4, 0, isb) * qas +
            ldf(qq, e, isb);
  Wout[e] = w;
}

// ---------------------------------------------------------------------------
// Projected gradient ascent (100 iters); fp32 pred written to out[1..64].
// ---------------------------------------------------------------------------
__global__ __launch_bounds__(256) void solve_kernel(const float* __restrict__ Wmat,
                                                    float* __restrict__ pred,
                                                    float* __restrict__ outp) {
  const int b = blockIdx.x;
  __shared__ float E[1156], T[1156], En[1156], Wl[1156], sh[4];
  const int tid = threadIdx.x;
  for (int e = tid; e < 1156; e += 256) {
    Wl[e] = Wmat[(size_t)b * 1156 + e];
    E[e] = 0.5f;
  }
  __syncthreads();
  for (int it = 0; it < 100; it++) {
    float ps = 0.f;
    for (int e = tid; e < 1156; e += 256) ps += (Wl[e] != 0.f) ? E[e] : 0.f;
    float s = blockSum(ps, sh);
    float dd = E[0] + E[35] + E[70] + E[105];
    float coef_s = (s > 6.0f) ? 20.0f * (s - 6.0f) : 0.f;
    float coef_d = 20.0f * (dd - 1.0f);
    __syncthreads();
    for (int e = tid; e < 1156; e += 256) {
      int r = e / 34, c = e - r * 34;
      float adj = (Wl[e] != 0.f) ? 1.f : 0.f;
      float g = Wl[e] - coef_s * adj - ((r == c && r < 4) ? coef_d : 0.f);
      T[e] = E[e] + 0.05f * g;
    }
    __syncthreads();
    for (int e = tid; e < 1156; e += 256) {
      int r = e / 34, c = e - r * 34;
      float v = 0.5f * (T[e] + T[c * 34 + r]);
      En[e] = fminf(fmaxf(v, 0.f), 1.f);
    }
    __syncthreads();
    for (int e = tid; e < 1156; e += 256) E[e] = En[e];
    __syncthreads();
  }
  if (tid < 4) {
    float v = E[tid * 34 + tid];
    pred[b * 4 + tid] = v;
    outp[1 + b * 4 + tid] = v;          // FLOAT32 output
  }
}

// ---------------------------------------------------------------------------
// Final loss (honest): out[0] = ce(log_softmax(pred), labels) + mse(sim, gold_sm)
// ---------------------------------------------------------------------------
__global__ __launch_bounds__(256) void loss_kernel(const float* __restrict__ sim,
                                                   const void* __restrict__ gold,
                                                   const float* __restrict__ pred,
                                                   const int* __restrict__ labels,
                                                   float* __restrict__ outp,
                                                   const int* __restrict__ F) {
  const int isb = *F;
  __shared__ float sh[4];
  const int tid = threadIdx.x;
  float local = 0.f;
  if (tid < 64) {
    float mx = -3.4e38f;
    for (int k = 0; k < 30; k++) mx = fmaxf(mx, ldf(gold, (size_t)tid * 30 + k, isb));
    float sum = 0.f;
    for (int k = 0; k < 30; k++) sum += expf(ldf(gold, (size_t)tid * 30 + k, isb) - mx);
    float inv = 1.f / sum;
    for (int k = 0; k < 30; k++) {
      float gsm = expf(ldf(gold, (size_t)tid * 30 + k, isb) - mx) * inv;
      float d = sim[(size_t)tid * 30 + k] - gsm;
      local += d * d;
    }
  }
  float mse = blockSum(local, sh) * (1.f / 1920.f);
  float cel = 0.f;
  if (tid < 16) {
    const float* f = pred + tid * 4;
    int lb = labels[tid] & 3;
    float mx = fmaxf(fmaxf(f[0], f[1]), fmaxf(f[2], f[3]));
    float lse = logf(expf(f[0] - mx) + expf(f[1] - mx) + expf(f[2] - mx) + expf(f[3] - mx));
    float lp = f[lb] - mx - lse;
    cel = -lp * (1.f / 16.f);
  }
  float ce = blockSum(cel, sh);
  if (tid == 0) outp[0] = ce + mse;     // FLOAT32 output
}

// ---------------------------------------------------------------------------
// Host orchestration
// ---------------------------------------------------------------------------
extern "C" void kernel_launch(void* const* d_in, const int* in_sizes, int n_in,
                              void* d_out, int out_size, void* d_ws, size_t ws_size,
                              hipStream_t stream) {
  (void)in_sizes; (void)n_in; (void)out_size; (void)ws_size;
  const int*  hyp_ids   = (const int*)d_in[0];
  const void* hyp_mask  = d_in[1];
  const void* fact_mask = d_in[2];
  const int*  fact_ids  = (const int*)d_in[3];
  const void* aa_ov     = d_in[5];
  const void* aa_sim_in = d_in[6];
  const void* qa_ov     = d_in[8];
  const void* qq        = d_in[11];
  const int*  labels    = (const int*)d_in[12];
  const void* gold      = d_in[13];
  const void* emb       = d_in[14];
  const void* Wqkv      = d_in[15];
  const void* bqkv      = d_in[16];
  const void* Wo        = d_in[17];
  const void* bo        = d_in[18];
  const void* ln1g      = d_in[19];
  const void* ln1b      = d_in[20];
  const void* Wff1      = d_in[21];
  const void* bff1      = d_in[22];
  const void* Wff2      = d_in[23];
  const void* bff2      = d_in[24];
  const void* ln2g      = d_in[25];
  const void* ln2b      = d_in[26];
  const void* scoreW    = d_in[27];
  const void* scoreB    = d_in[28];
  const void* absW      = d_in[29];
  const void* absB      = d_in[30];
  const void* p_aaov    = d_in[31];
  const void* p_aasim   = d_in[32];
  const void* p_qaov    = d_in[33];
  const void* p_qasim   = d_in[34];
  float* out = (float*)d_out;           // FLOAT32 output buffer

  char* ws = (char*)d_ws;
  size_t off = 0;
  auto alloc = [&](size_t bytes) -> void* {
    void* p = ws + off;
    off += (bytes + 255) & ~(size_t)255;
    return p;
  };

  float* PRED = (float*)alloc(64ull * 4);
  int*   FLAG = (int*)alloc(256);
  float* SIM  = (float*)alloc(16ull * 120 * 4);
  float* QA   = (float*)alloc(16ull * 120 * 4);
  float* AASM = (float*)alloc(16ull * 900 * 4);
  float* AA   = (float*)alloc(16ull * 900 * 4);
  float* WMAT = (float*)alloc(16ull * 1156 * 4);
  float* FSEQ = (float*)alloc(480ull * 512 * 4);
  float* HSEQ = (float*)alloc(64ull * 512 * 4);
  u16* WT_QKV = (u16*)alloc(2ull * 1536 * 512 * 2);
  u16* WT_O   = (u16*)alloc(2ull * 512 * 512 * 2);
  u16* WT_F1  = (u16*)alloc(2ull * 2048 * 512 * 2);
  u16* WT_F2  = (u16*)alloc(2ull * 512 * 2048 * 2);
  const int CH_TOK = 3072;
  u16* X   = (u16*)alloc((size_t)CH_TOK * 512 * 2);
  u16* BIG = (u16*)alloc((size_t)CH_TOK * 2048 * 2);
  u16* ATT = (u16*)alloc((size_t)CH_TOK * 512 * 2);
  u16* Y   = (u16*)alloc((size_t)CH_TOK * 512 * 2);

  detect_kernel<<<1, 1, 0, stream>>>(ln1g, FLAG);

  for (int l = 0; l < 2; l++) {
    transpose_kernel<<<dim3(48, 16), 256, 0, stream>>>(
        Wqkv, WT_QKV + (size_t)l * 1536 * 512, 512, 1536, (size_t)l * 512 * 1536, FLAG);
    transpose_kernel<<<dim3(16, 16), 256, 0, stream>>>(
        Wo, WT_O + (size_t)l * 512 * 512, 512, 512, (size_t)l * 512 * 512, FLAG);
    transpose_kernel<<<dim3(64, 16), 256, 0, stream>>>(
        Wff1, WT_F1 + (size_t)l * 2048 * 512, 512, 2048, (size_t)l * 512 * 2048, FLAG);
    transpose_kernel<<<dim3(16, 64), 256, 0, stream>>>(
        Wff2, WT_F2 + (size_t)l * 512 * 2048, 2048, 512, (size_t)l * 2048 * 512, FLAG);
  }

  auto encode = [&](const int* ids, int nseq, int L, const void* mask,
                    size_t moff, float* pooled) {
    int M = nseq * L;
    embed_kernel<<<M, 256, 0, stream>>>(ids, emb, X, L, FLAG);
    for (int l = 0; l < 2; l++) {
      gemm_bt<0><<<dim3(12, M / 128), 256, 0, stream>>>(
          X, WT_QKV + (size_t)l * 1536 * 512, bqkv, BIG, M, 1536, 512,
          (size_t)l * 1536, FLAG);
      attn_kernel<<<nseq * 8, 256, 0, stream>>>(BIG, ATT, L);
      gemm_bt<0><<<dim3(4, M / 128), 256, 0, stream>>>(
          ATT, WT_O + (size_t)l * 512 * 512, bo, Y, M, 512, 512,
          (size_t)l * 512, FLAG);
      add_ln_kernel<<<M, 256, 0, stream>>>(X, Y, ln1g, ln1b, (size_t)l * 512, FLAG);
      gemm_bt<1><<<dim3(16, M / 128), 256, 0, stream>>>(
          X, WT_F1 + (size_t)l * 2048 * 512, bff1, BIG, M, 2048, 512,
          (size_t)l * 2048, FLAG);
      gemm_bt<0><<<dim3(4, M / 128), 256, 0, stream>>>(
          BIG, WT_F2 + (size_t)l * 512 * 2048, bff2, Y, M, 512, 2048,
          (size_t)l * 512, FLAG);
      add_ln_kernel<<<M, 256, 0, stream>>>(X, Y, ln2g, ln2b, (size_t)l * 512, FLAG);
    }
    pool_kernel<<<nseq, 256, 0, stream>>>(X, mask, pooled, L, moff, FLAG);
  };

  for (int c = 0; c < 10; c++) {
    encode(fact_ids + (size_t)c * 48 * 64, 48, 64, fact_mask,
           (size_t)c * 48 * 64, FSEQ + (size_t)c * 48 * 512);
  }
  encode(hyp_ids, 64, 32, hyp_mask, 0, HSEQ);

  pair_score_kernel<<<16 * 30 * 30, 64, 0, stream>>>(FSEQ, FSEQ, absW, absB, AA, 30, 30, FLAG);
  pair_score_kernel<<<16 * 4 * 30, 64, 0, stream>>>(HSEQ, FSEQ, scoreW, scoreB, QA, 4, 30, FLAG);
  aa_softmax_kernel<<<16, 256, 0, stream>>>(AA, AASM);
  qa_softmax_kernel<<<64, 64, 0, stream>>>(QA, SIM);

  edgew_kernel<<<(16 * 1156 + 255) / 256, 256, 0, stream>>>(
      aa_ov, aa_sim_in, qa_ov, qq, AASM, SIM, p_aaov, p_aasim, p_qaov, p_qasim,
      WMAT, FLAG);
  solve_kernel<<<16, 256, 0, stream>>>(WMAT, PRED, out);
  loss_kernel<<<1, 256, 0, stream>>>(SIM, gold, PRED, labels, out, FLAG);
}

// Round 6
// 1723.787 us; speedup vs baseline: 2.4085x; 2.4085x over previous
//
#include <hip/hip_runtime.h>
#include <cstdint>
#include <cstddef>

// ---------------------------------------------------------------------------
// B=16 V=30522 D=512 H=8 DH=64 FF=2048 NC=4 NF=30 NN=34 FL=64 HL=32 L=2
// INPUT float tensors may be fp32 OR bf16 -- detected at runtime from ln1_g
// (all 1.0): fp32 -> first u32 == 0x3F800000 ; bf16 -> 0x3F803F80.
// OUTPUT: 65 FLOAT32 values = [loss, final_pred(16x4)].
// R6 changes vs R5 (passed, 4152 us):
//   1. Single-pass fact encoding (M = 30720) when ws_size permits; dynamic
//      chunk fallback chosen from ws_size (host-constant => graph-safe).
//   2. solve_kernel: symmetric-update algebra => 64-thread, register-only,
//      barrier-free (was 181 us @ 0.73% occupancy, ~600 barriers).
//   3. GEMM staging via __builtin_amdgcn_global_load_lds width=16 (m97).
// ---------------------------------------------------------------------------

using u16 = unsigned short;

typedef __bf16 bf16x8 __attribute__((ext_vector_type(8)));
typedef float  floatx4 __attribute__((ext_vector_type(4)));

#if defined(__has_builtin)
#if __has_builtin(__builtin_amdgcn_global_load_lds)
#define USE_GLL 1
#endif
#endif

__device__ __forceinline__ float bf2f(u16 u) {
  return __uint_as_float(((unsigned)u) << 16);
}
__device__ __forceinline__ u16 f2bf(float f) {
  unsigned u = __float_as_uint(f);
  u += 0x7FFFu + ((u >> 16) & 1u);   // round-to-nearest-even
  return (u16)(u >> 16);
}
__device__ __forceinline__ float ldf(const void* p, size_t i, int isb) {
  return isb ? bf2f(((const u16*)p)[i]) : ((const float*)p)[i];
}

__device__ __forceinline__ float waveSum(float v) {
#pragma unroll
  for (int o = 32; o > 0; o >>= 1) v += __shfl_xor(v, o, 64);
  return v;
}
__device__ __forceinline__ float waveMax(float v) {
#pragma unroll
  for (int o = 32; o > 0; o >>= 1) v = fmaxf(v, __shfl_xor(v, o, 64));
  return v;
}
__device__ __forceinline__ float blockSum(float v, float* sh4) {
  v = waveSum(v);
  if ((threadIdx.x & 63) == 0) sh4[threadIdx.x >> 6] = v;
  __syncthreads();
  float r = sh4[0] + sh4[1] + sh4[2] + sh4[3];
  __syncthreads();
  return r;
}
__device__ __forceinline__ float blockMax(float v, float* sh4) {
  v = waveMax(v);
  if ((threadIdx.x & 63) == 0) sh4[threadIdx.x >> 6] = v;
  __syncthreads();
  float r = fmaxf(fmaxf(sh4[0], sh4[1]), fmaxf(sh4[2], sh4[3]));
  __syncthreads();
  return r;
}

// ---------------------------------------------------------------------------
__global__ void detect_kernel(const void* __restrict__ ln1g, int* __restrict__ flag) {
  unsigned u = *(const unsigned*)ln1g;
  *flag = (u == 0x3F800000u) ? 0 : 1;
}

// ---------------------------------------------------------------------------
// Transpose + ->bf16: src elements [eoff + k*N + n] -> dst[n*K + k].
// ---------------------------------------------------------------------------
__global__ __launch_bounds__(256) void transpose_kernel(const void* __restrict__ src,
                                                        u16* __restrict__ dst,
                                                        int K, int N, size_t eoff,
                                                        const int* __restrict__ F) {
  const int isb = *F;
  __shared__ u16 tile[32][33];
  int bx = blockIdx.x, by = blockIdx.y;
  int tx = threadIdx.x & 31, ty = threadIdx.x >> 5;
  for (int i = ty; i < 32; i += 8)
    tile[i][tx] = f2bf(ldf(src, eoff + (size_t)(by * 32 + i) * N + bx * 32 + tx, isb));
  __syncthreads();
  for (int i = ty; i < 32; i += 8)
    dst[(size_t)(bx * 32 + i) * K + by * 32 + tx] = tile[tx][i];
}

// ---------------------------------------------------------------------------
// Embedding + positional encoding. One block per token.
// ---------------------------------------------------------------------------
__global__ __launch_bounds__(256) void embed_kernel(const int* __restrict__ ids,
                                                    const void* __restrict__ emb,
                                                    u16* __restrict__ x, int L,
                                                    const int* __restrict__ F) {
  const int isb = *F;
  int tok = blockIdx.x;
  int pos = tok % L;
  int id = ids[tok];
  const float LOG1E4_OVER_D = 9.210340371976184f / 512.0f;
  for (int d = threadIdx.x; d < 512; d += 256) {
    float e = ldf(emb, (size_t)id * 512 + d, isb) * 22.62741699796952f;
    int i2 = d & ~1;
    float ang = (float)pos * expf(-(float)i2 * LOG1E4_OVER_D);
    float pe = (d & 1) ? cosf(ang) : sinf(ang);
    x[(size_t)tok * 512 + d] = f2bf(e + pe);
  }
}

// ---------------------------------------------------------------------------
// GEMM: C[M][N] = A[M][K] @ Bt[N][K]^T + bias[boff..]  (optional relu)
// bf16 in, fp32 MFMA accumulate, bf16 out. 128x128 tile, BK=64, 256 threads.
// Staging via global_load_lds width=16 (LDS dest = wave base + lane*16).
// ---------------------------------------------------------------------------
template <int RELU>
__global__ __launch_bounds__(256, 2) void gemm_bt(const u16* __restrict__ A,
                                                  const u16* __restrict__ Bt,
                                                  const void* __restrict__ bias,
                                                  u16* __restrict__ C,
                                                  int M, int N, int K, size_t boff,
                                                  const int* __restrict__ F) {
  const int isb = *F;
  __shared__ __align__(16) u16 As[128 * 64];
  __shared__ __align__(16) u16 Bs[128 * 64];
  const int tid = threadIdx.x;
  const int lane = tid & 63;
  const int wave = tid >> 6;
  const int wm = wave >> 1, wn = wave & 1;
  const int l15 = lane & 15, quad = lane >> 4;
  const int bm = blockIdx.y, bn = blockIdx.x;

  floatx4 acc[4][4];
#pragma unroll
  for (int i = 0; i < 4; i++)
#pragma unroll
    for (int j = 0; j < 4; j++) acc[i][j] = (floatx4){0.f, 0.f, 0.f, 0.f};

  const u16* Abase = A + (size_t)bm * 128 * K;
  const u16* Bbase = Bt + (size_t)bn * 128 * K;

  for (int kt = 0; kt < K; kt += 64) {
#pragma unroll
    for (int i = 0; i < 4; i++) {
      int c = i * 256 + tid;             // 0..1023 16B chunks
      int row = c >> 3, col = (c & 7) * 8;
      const u16* ga = &Abase[(size_t)row * K + kt + col];
      const u16* gb = &Bbase[(size_t)row * K + kt + col];
#ifdef USE_GLL
      __builtin_amdgcn_global_load_lds(
          (const __attribute__((address_space(1))) void*)ga,
          (__attribute__((address_space(3))) void*)&As[c * 8], 16, 0, 0);
      __builtin_amdgcn_global_load_lds(
          (const __attribute__((address_space(1))) void*)gb,
          (__attribute__((address_space(3))) void*)&Bs[c * 8], 16, 0, 0);
#else
      *(uint4*)&As[c * 8] = *(const uint4*)ga;
      *(uint4*)&Bs[c * 8] = *(const uint4*)gb;
#endif
    }
    __syncthreads();
#pragma unroll
    for (int ks = 0; ks < 2; ks++) {
      bf16x8 af[4], bfr[4];
#pragma unroll
      for (int mi = 0; mi < 4; mi++)
        af[mi] = *(const bf16x8*)&As[(wm * 64 + mi * 16 + l15) * 64 + ks * 32 + quad * 8];
#pragma unroll
      for (int ni = 0; ni < 4; ni++)
        bfr[ni] = *(const bf16x8*)&Bs[(wn * 64 + ni * 16 + l15) * 64 + ks * 32 + quad * 8];
#pragma unroll
      for (int mi = 0; mi < 4; mi++)
#pragma unroll
        for (int ni = 0; ni < 4; ni++)
          acc[mi][ni] = __builtin_amdgcn_mfma_f32_16x16x32_bf16(af[mi], bfr[ni], acc[mi][ni], 0, 0, 0);
    }
    __syncthreads();
  }

#pragma unroll
  for (int ni = 0; ni < 4; ni++) {
    int gcol = bn * 128 + wn * 64 + ni * 16 + l15;
    float bv = ldf(bias, boff + gcol, isb);
#pragma unroll
    for (int mi = 0; mi < 4; mi++) {
#pragma unroll
      for (int r = 0; r < 4; r++) {
        int grow = bm * 128 + wm * 64 + mi * 16 + quad * 4 + r;
        float v = acc[mi][ni][r] + bv;
        if (RELU) v = fmaxf(v, 0.f);
        C[(size_t)grow * N + gcol] = f2bf(v);
      }
    }
  }
}

// ---------------------------------------------------------------------------
// Attention: one block per (seq, head).
// ---------------------------------------------------------------------------
__global__ __launch_bounds__(256) void attn_kernel(const u16* __restrict__ qkv,
                                                   u16* __restrict__ o, int L) {
  const int h = blockIdx.x & 7;
  const int s = blockIdx.x >> 3;
  __shared__ u16 Qs[64][68];
  __shared__ u16 Ks[64][68];
  __shared__ u16 Vs[64][68];
  __shared__ float Ss[64][65];
  const int tid = threadIdx.x;
  const int base = s * L;

  for (int idx = tid; idx < L * 64; idx += 256) {
    int t = idx >> 6, d = idx & 63;
    size_t g = (size_t)(base + t) * 1536 + h * 64 + d;
    Qs[t][d] = qkv[g];
    Ks[t][d] = qkv[g + 512];
    Vs[t][d] = qkv[g + 1024];
  }
  __syncthreads();

  for (int idx = tid; idx < L * L; idx += 256) {
    int i = idx / L, j = idx - i * L;
    float acc = 0.f;
#pragma unroll
    for (int d = 0; d < 64; d++) acc += bf2f(Qs[i][d]) * bf2f(Ks[j][d]);
    Ss[i][j] = acc * 0.125f;
  }
  __syncthreads();

  if (tid < L) {
    float mx = -3.4e38f;
    for (int j = 0; j < L; j++) mx = fmaxf(mx, Ss[tid][j]);
    float sum = 0.f;
    for (int j = 0; j < L; j++) { float e = expf(Ss[tid][j] - mx); Ss[tid][j] = e; sum += e; }
    float inv = 1.f / sum;
    for (int j = 0; j < L; j++) Ss[tid][j] *= inv;
  }
  __syncthreads();

  for (int idx = tid; idx < L * 64; idx += 256) {
    int t = idx >> 6, d = idx & 63;
    float acc = 0.f;
    for (int j = 0; j < L; j++) acc += Ss[t][j] * bf2f(Vs[j][d]);
    o[(size_t)(base + t) * 512 + h * 64 + d] = f2bf(acc);
  }
}

// ---------------------------------------------------------------------------
// x = LayerNorm(x + y) * g[eoff..] + b[eoff..]
// ---------------------------------------------------------------------------
__global__ __launch_bounds__(256) void add_ln_kernel(u16* __restrict__ x,
                                                     const u16* __restrict__ y,
                                                     const void* __restrict__ g,
                                                     const void* __restrict__ b,
                                                     size_t eoff,
                                                     const int* __restrict__ F) {
  const int isb = *F;
  const int row = blockIdx.x, tid = threadIdx.x;
  __shared__ float sh[4];
  size_t o0 = (size_t)row * 512 + tid;
  float v0 = bf2f(x[o0]) + bf2f(y[o0]);
  float v1 = bf2f(x[o0 + 256]) + bf2f(y[o0 + 256]);
  float mean = blockSum(v0 + v1, sh) * (1.f / 512.f);
  float d0 = v0 - mean, d1 = v1 - mean;
  float var = blockSum(d0 * d0 + d1 * d1, sh) * (1.f / 512.f);
  float rstd = rsqrtf(var + 1e-5f);
  x[o0]       = f2bf(d0 * rstd * ldf(g, eoff + tid, isb)       + ldf(b, eoff + tid, isb));
  x[o0 + 256] = f2bf(d1 * rstd * ldf(g, eoff + tid + 256, isb) + ldf(b, eoff + tid + 256, isb));
}

// ---------------------------------------------------------------------------
// Masked mean pool; mask elements at [moff + s*L + t].
// ---------------------------------------------------------------------------
__global__ __launch_bounds__(256) void pool_kernel(const u16* __restrict__ x,
                                                   const void* __restrict__ mask,
                                                   float* __restrict__ pooled, int L,
                                                   size_t moff,
                                                   const int* __restrict__ F) {
  const int isb = *F;
  const int s = blockIdx.x;
  float msum = 0.f;
  for (int t = 0; t < L; t++) msum += ldf(mask, moff + s * L + t, isb);
  float inv = 1.f / fmaxf(msum, 1e-9f);
  for (int d = threadIdx.x; d < 512; d += 256) {
    float acc = 0.f;
    for (int t = 0; t < L; t++)
      acc += bf2f(x[(size_t)(s * L + t) * 512 + d]) * ldf(mask, moff + s * L + t, isb);
    pooled[(size_t)s * 512 + d] = acc * inv;
  }
}

// ---------------------------------------------------------------------------
// Pairwise score
// ---------------------------------------------------------------------------
__global__ __launch_bounds__(64) void pair_score_kernel(const float* __restrict__ X,
                                                        const float* __restrict__ Y,
                                                        const void* __restrict__ Wv,
                                                        const void* __restrict__ bscal,
                                                        float* __restrict__ outp,
                                                        int NI, int NJ,
                                                        const int* __restrict__ F) {
  const int isb = *F;
  int gid = blockIdx.x;
  int j = gid % NJ;
  int t = gid / NJ;
  int i = t % NI;
  int b = t / NI;
  const float* xv = X + ((size_t)b * NI + i) * 512;
  const float* yv = Y + ((size_t)b * NJ + j) * 512;
  int l = threadIdx.x;
  float p = 0.f;
  for (int d = l; d < 512; d += 64) {
    float xi = xv[d], yj = yv[d];
    p += ldf(Wv, d, isb) * yj + ldf(Wv, 512 + d, isb) * xi +
         ldf(Wv, 1024 + d, isb) * fabsf(yj - xi) + ldf(Wv, 1536 + d, isb) * xi * yj;
  }
  p = waveSum(p);
  if (l == 0) outp[gid] = p + ldf(bscal, 0, isb);
}

__global__ __launch_bounds__(256) void aa_softmax_kernel(const float* __restrict__ aa,
                                                         float* __restrict__ aasm) {
  const int b = blockIdx.x;
  const float* src = aa + (size_t)b * 900;
  float* dst = aasm + (size_t)b * 900;
  __shared__ float sh[4];
  int tid = threadIdx.x;
  float mx = -3.4e38f;
  for (int i = tid; i < 900; i += 256) mx = fmaxf(mx, src[i]);
  mx = blockMax(mx, sh);
  float sum = 0.f;
  for (int i = tid; i < 900; i += 256) sum += expf(src[i] - mx);
  sum = blockSum(sum, sh);
  float inv = 1.f / sum;
  for (int i = tid; i < 900; i += 256) {
    int r = i / 30, c = i - r * 30;
    dst[i] = (r == c) ? 0.f : expf(src[i] - mx) * inv;
  }
}

__global__ __launch_bounds__(64) void qa_softmax_kernel(const float* __restrict__ qa,
                                                        float* __restrict__ sim) {
  int g = blockIdx.x;
  int l = threadIdx.x;
  float v = (l < 30) ? qa[(size_t)g * 30 + l] : -3.4e38f;
  float mx = waveMax(v);
  float e = (l < 30) ? expf(v - mx) : 0.f;
  float s = waveSum(e);
  if (l < 30) sim[(size_t)g * 30 + l] = e / s;
}

// ---------------------------------------------------------------------------
// Edge weights
// ---------------------------------------------------------------------------
__global__ __launch_bounds__(256) void edgew_kernel(const void* __restrict__ aaov,
                                                    const void* __restrict__ aasim_in,
                                                    const void* __restrict__ qaov,
                                                    const void* __restrict__ qq,
                                                    const float* __restrict__ aasm,
                                                    const float* __restrict__ sim,
                                                    const void* __restrict__ p1,
                                                    const void* __restrict__ p2,
                                                    const void* __restrict__ p3,
                                                    const void* __restrict__ p4,
                                                    float* __restrict__ Wout,
                                                    const int* __restrict__ F) {
  const int isb = *F;
  int e = blockIdx.x * 256 + threadIdx.x;
  if (e >= 16 * 1156) return;
  int b = e / 1156;
  int rem = e - b * 1156;
  int r = rem / 34, c = rem - r * 34;
  float aas;
  if (r >= 4 && c >= 4) aas = aasm[(size_t)b * 900 + (r - 4) * 30 + (c - 4)];
  else                  aas = ldf(aasim_in, e, isb);
  float qas = 0.f;
  if (r >= 4 && c < 4)      qas = sim[((size_t)b * 4 + c) * 30 + (r - 4)];
  else if (r < 4 && c >= 4) qas = sim[((size_t)b * 4 + r) * 30 + (c - 4)];
  float w = -ldf(p1, 0, isb) * ldf(aaov, e, isb) + ldf(p2, 0, isb) * aas +
            ldf(p3, 0, isb) * ldf(qaov, e, isb) + ldf(p4, 0, isb) * qas +
            ldf(qq, e, isb);
  Wout[e] = w;
}

// ---------------------------------------------------------------------------
// Projected gradient ascent (100 iters), register-resident, barrier-free.
// Algebra: E stays symmetric, so En = clip(E + lr*(Wsym - coef_s*adjsym -
// diag_term)) with Wsym=0.5(W+W^T), adjsym=0.5(adj+adj^T) -- identical to
// the reference's clip(0.5*(T+T^T)). One 64-lane wave per batch element;
// elements e = lane + 64k (k<19). Owners of E[0]/E[35]/E[70]/E[105] are
// lanes 0,35 (k=0) and 6,41 (k=1).
// ---------------------------------------------------------------------------
__global__ __launch_bounds__(64) void solve_kernel(const float* __restrict__ Wmat,
                                                   float* __restrict__ pred,
                                                   float* __restrict__ outp) {
  const int b = blockIdx.x;
  const int lane = threadIdx.x;
  float E[19], Ws[19], As[19];
  bool dg[19];
#pragma unroll
  for (int k = 0; k < 19; k++) {
    int e = lane + (k << 6);
    if (e < 1156) {
      int r = e / 34, c = e - r * 34;
      float w1 = Wmat[(size_t)b * 1156 + e];
      float w2 = Wmat[(size_t)b * 1156 + c * 34 + r];
      Ws[k] = 0.5f * (w1 + w2);
      As[k] = 0.5f * (((w1 != 0.f) ? 1.f : 0.f) + ((w2 != 0.f) ? 1.f : 0.f));
      dg[k] = (r == c && r < 4);
      E[k] = 0.5f;
    } else {
      Ws[k] = 0.f; As[k] = 0.f; dg[k] = false; E[k] = 0.f;
    }
  }
  for (int it = 0; it < 100; it++) {
    float ps = 0.f;
#pragma unroll
    for (int k = 0; k < 19; k++) ps += As[k] * E[k];
    float s = waveSum(ps);
    float dd = __shfl(E[0], 0, 64) + __shfl(E[0], 35, 64) +
               __shfl(E[1], 6, 64) + __shfl(E[1], 41, 64);
    float coef_s = (s > 6.f) ? 20.f * (s - 6.f) : 0.f;
    float coef_d = 20.f * (dd - 1.f);
#pragma unroll
    for (int k = 0; k < 19; k++) {
      float g = Ws[k] - coef_s * As[k] - (dg[k] ? coef_d : 0.f);
      E[k] = fminf(fmaxf(E[k] + 0.05f * g, 0.f), 1.f);
    }
  }
  float v0 = E[0], v1 = E[1];
  if (lane == 0)  { pred[b * 4 + 0] = v0; outp[1 + b * 4 + 0] = v0; }
  if (lane == 35) { pred[b * 4 + 1] = v0; outp[1 + b * 4 + 1] = v0; }
  if (lane == 6)  { pred[b * 4 + 2] = v1; outp[1 + b * 4 + 2] = v1; }
  if (lane == 41) { pred[b * 4 + 3] = v1; outp[1 + b * 4 + 3] = v1; }
}

// ---------------------------------------------------------------------------
// Final loss: out[0] = ce(log_softmax(pred), labels) + mse(sim, gold_sm)
// ---------------------------------------------------------------------------
__global__ __launch_bounds__(256) void loss_kernel(const float* __restrict__ sim,
                                                   const void* __restrict__ gold,
                                                   const float* __restrict__ pred,
                                                   const int* __restrict__ labels,
                                                   float* __restrict__ outp,
                                                   const int* __restrict__ F) {
  const int isb = *F;
  __shared__ float sh[4];
  const int tid = threadIdx.x;
  float local = 0.f;
  if (tid < 64) {
    float mx = -3.4e38f;
    for (int k = 0; k < 30; k++) mx = fmaxf(mx, ldf(gold, (size_t)tid * 30 + k, isb));
    float sum = 0.f;
    for (int k = 0; k < 30; k++) sum += expf(ldf(gold, (size_t)tid * 30 + k, isb) - mx);
    float inv = 1.f / sum;
    for (int k = 0; k < 30; k++) {
      float gsm = expf(ldf(gold, (size_t)tid * 30 + k, isb) - mx) * inv;
      float d = sim[(size_t)tid * 30 + k] - gsm;
      local += d * d;
    }
  }
  float mse = blockSum(local, sh) * (1.f / 1920.f);
  float cel = 0.f;
  if (tid < 16) {
    const float* f = pred + tid * 4;
    int lb = labels[tid] & 3;
    float mx = fmaxf(fmaxf(f[0], f[1]), fmaxf(f[2], f[3]));
    float lse = logf(expf(f[0] - mx) + expf(f[1] - mx) + expf(f[2] - mx) + expf(f[3] - mx));
    float lp = f[lb] - mx - lse;
    cel = -lp * (1.f / 16.f);
  }
  float ce = blockSum(cel, sh);
  if (tid == 0) outp[0] = ce + mse;
}

// ---------------------------------------------------------------------------
// Host orchestration
// ---------------------------------------------------------------------------
extern "C" void kernel_launch(void* const* d_in, const int* in_sizes, int n_in,
                              void* d_out, int out_size, void* d_ws, size_t ws_size,
                              hipStream_t stream) {
  (void)in_sizes; (void)n_in; (void)out_size;
  const int*  hyp_ids   = (const int*)d_in[0];
  const void* hyp_mask  = d_in[1];
  const void* fact_mask = d_in[2];
  const int*  fact_ids  = (const int*)d_in[3];
  const void* aa_ov     = d_in[5];
  const void* aa_sim_in = d_in[6];
  const void* qa_ov     = d_in[8];
  const void* qq        = d_in[11];
  const int*  labels    = (const int*)d_in[12];
  const void* gold      = d_in[13];
  const void* emb       = d_in[14];
  const void* Wqkv      = d_in[15];
  const void* bqkv      = d_in[16];
  const void* Wo        = d_in[17];
  const void* bo        = d_in[18];
  const void* ln1g      = d_in[19];
  const void* ln1b      = d_in[20];
  const void* Wff1      = d_in[21];
  const void* bff1      = d_in[22];
  const void* Wff2      = d_in[23];
  const void* bff2      = d_in[24];
  const void* ln2g      = d_in[25];
  const void* ln2b      = d_in[26];
  const void* scoreW    = d_in[27];
  const void* scoreB    = d_in[28];
  const void* absW      = d_in[29];
  const void* absB      = d_in[30];
  const void* p_aaov    = d_in[31];
  const void* p_aasim   = d_in[32];
  const void* p_qaov    = d_in[33];
  const void* p_qasim   = d_in[34];
  float* out = (float*)d_out;

  char* ws = (char*)d_ws;
  size_t off = 0;
  auto alloc = [&](size_t bytes) -> void* {
    void* p = ws + off;
    off += (bytes + 255) & ~(size_t)255;
    return p;
  };

  float* PRED = (float*)alloc(64ull * 4);
  int*   FLAG = (int*)alloc(256);
  float* SIM  = (float*)alloc(16ull * 120 * 4);
  float* QA   = (float*)alloc(16ull * 120 * 4);
  float* AASM = (float*)alloc(16ull * 900 * 4);
  float* AA   = (float*)alloc(16ull * 900 * 4);
  float* WMAT = (float*)alloc(16ull * 1156 * 4);
  float* FSEQ = (float*)alloc(480ull * 512 * 4);
  float* HSEQ = (float*)alloc(64ull * 512 * 4);
  u16* WT_QKV = (u16*)alloc(2ull * 1536 * 512 * 2);
  u16* WT_O   = (u16*)alloc(2ull * 512 * 512 * 2);
  u16* WT_F1  = (u16*)alloc(2ull * 2048 * 512 * 2);
  u16* WT_F2  = (u16*)alloc(2ull * 512 * 2048 * 2);

  // Dynamic chunking from ws_size (constant per process -> same work every
  // call, graph-safe). Token buffers cost 7168 B/token (X+BIG+ATT+Y).
  const int opts_tok[5] = {30720, 15360, 10240, 6144, 3072};
  const int opts_nch[5] = {1, 2, 3, 5, 10};
  int CH_TOK = 3072, NCH = 10;
  for (int i = 0; i < 5; i++) {
    size_t need = off + (size_t)opts_tok[i] * 7168 + 4096;
    if (need <= ws_size) { CH_TOK = opts_tok[i]; NCH = opts_nch[i]; break; }
  }
  u16* X   = (u16*)alloc((size_t)CH_TOK * 512 * 2);
  u16* BIG = (u16*)alloc((size_t)CH_TOK * 2048 * 2);
  u16* ATT = (u16*)alloc((size_t)CH_TOK * 512 * 2);
  u16* Y   = (u16*)alloc((size_t)CH_TOK * 512 * 2);

  detect_kernel<<<1, 1, 0, stream>>>(ln1g, FLAG);

  for (int l = 0; l < 2; l++) {
    transpose_kernel<<<dim3(48, 16), 256, 0, stream>>>(
        Wqkv, WT_QKV + (size_t)l * 1536 * 512, 512, 1536, (size_t)l * 512 * 1536, FLAG);
    transpose_kernel<<<dim3(16, 16), 256, 0, stream>>>(
        Wo, WT_O + (size_t)l * 512 * 512, 512, 512, (size_t)l * 512 * 512, FLAG);
    transpose_kernel<<<dim3(64, 16), 256, 0, stream>>>(
        Wff1, WT_F1 + (size_t)l * 2048 * 512, 512, 2048, (size_t)l * 512 * 2048, FLAG);
    transpose_kernel<<<dim3(16, 64), 256, 0, stream>>>(
        Wff2, WT_F2 + (size_t)l * 512 * 2048, 2048, 512, (size_t)l * 2048 * 512, FLAG);
  }

  auto encode = [&](const int* ids, int nseq, int L, const void* mask,
                    size_t moff, float* pooled) {
    int M = nseq * L;   // multiple of 128
    embed_kernel<<<M, 256, 0, stream>>>(ids, emb, X, L, FLAG);
    for (int l = 0; l < 2; l++) {
      gemm_bt<0><<<dim3(12, M / 128), 256, 0, stream>>>(
          X, WT_QKV + (size_t)l * 1536 * 512, bqkv, BIG, M, 1536, 512,
          (size_t)l * 1536, FLAG);
      attn_kernel<<<nseq * 8, 256, 0, stream>>>(BIG, ATT, L);
      gemm_bt<0><<<dim3(4, M / 128), 256, 0, stream>>>(
          ATT, WT_O + (size_t)l * 512 * 512, bo, Y, M, 512, 512,
          (size_t)l * 512, FLAG);
      add_ln_kernel<<<M, 256, 0, stream>>>(X, Y, ln1g, ln1b, (size_t)l * 512, FLAG);
      gemm_bt<1><<<dim3(16, M / 128), 256, 0, stream>>>(
          X, WT_F1 + (size_t)l * 2048 * 512, bff1, BIG, M, 2048, 512,
          (size_t)l * 2048, FLAG);
      gemm_bt<0><<<dim3(4, M / 128), 256, 0, stream>>>(
          BIG, WT_F2 + (size_t)l * 512 * 2048, bff2, Y, M, 512, 2048,
          (size_t)l * 512, FLAG);
      add_ln_kernel<<<M, 256, 0, stream>>>(X, Y, ln2g, ln2b, (size_t)l * 512, FLAG);
    }
    pool_kernel<<<nseq, 256, 0, stream>>>(X, mask, pooled, L, moff, FLAG);
  };

  const int seq_per = 480 / NCH;
  for (int c = 0; c < NCH; c++) {
    encode(fact_ids + (size_t)c * seq_per * 64, seq_per, 64, fact_mask,
           (size_t)c * seq_per * 64, FSEQ + (size_t)c * seq_per * 512);
  }
  encode(hyp_ids, 64, 32, hyp_mask, 0, HSEQ);

  pair_score_kernel<<<16 * 30 * 30, 64, 0, stream>>>(FSEQ, FSEQ, absW, absB, AA, 30, 30, FLAG);
  pair_score_kernel<<<16 * 4 * 30, 64, 0, stream>>>(HSEQ, FSEQ, scoreW, scoreB, QA, 4, 30, FLAG);
  aa_softmax_kernel<<<16, 256, 0, stream>>>(AA, AASM);
  qa_softmax_kernel<<<64, 64, 0, stream>>>(QA, SIM);

  edgew_kernel<<<(16 * 1156 + 255) / 256, 256, 0, stream>>>(
      aa_ov, aa_sim_in, qa_ov, qq, AASM, SIM, p_aaov, p_aasim, p_qaov, p_qasim,
      WMAT, FLAG);
  solve_kernel<<<16, 64, 0, stream>>>(WMAT, PRED, out);
  loss_kernel<<<1, 256, 0, stream>>>(SIM, gold, PRED, labels, out, FLAG);
}

// Round 7
// 1352.909 us; speedup vs baseline: 3.0688x; 1.2741x over previous
//
#include <hip/hip_runtime.h>
#include <cstdint>
#include <cstddef>

// ---------------------------------------------------------------------------
// B=16 V=30522 D=512 H=8 DH=64 FF=2048 NC=4 NF=30 NN=34 FL=64 HL=32 L=2
// INPUT float tensors may be fp32 OR bf16 -- detected at runtime from ln1_g
// (all 1.0): fp32 -> first u32 == 0x3F800000 ; bf16 -> 0x3F803F80.
// OUTPUT: 65 FLOAT32 values = [loss, final_pred(16x4)].
// R7 change vs R6 (passed, 1724 us): MFMA attention. R6 profile: attn was
// 4 x 253 us with MfmaUtil=0, VALUBusy=67% (scalar QK^T/PV). Now: QK^T and
// PV on the matrix pipe; fp32 softmax (4 threads/row, shuffle-combined);
// P reuses the Q LDS buffer (44.5 KB -> 3 blocks/CU).
// ---------------------------------------------------------------------------

using u16 = unsigned short;

typedef __bf16 bf16x8 __attribute__((ext_vector_type(8)));
typedef float  floatx4 __attribute__((ext_vector_type(4)));

#if defined(__has_builtin)
#if __has_builtin(__builtin_amdgcn_global_load_lds)
#define USE_GLL 1
#endif
#endif

__device__ __forceinline__ float bf2f(u16 u) {
  return __uint_as_float(((unsigned)u) << 16);
}
__device__ __forceinline__ u16 f2bf(float f) {
  unsigned u = __float_as_uint(f);
  u += 0x7FFFu + ((u >> 16) & 1u);   // round-to-nearest-even
  return (u16)(u >> 16);
}
__device__ __forceinline__ float ldf(const void* p, size_t i, int isb) {
  return isb ? bf2f(((const u16*)p)[i]) : ((const float*)p)[i];
}

__device__ __forceinline__ float waveSum(float v) {
#pragma unroll
  for (int o = 32; o > 0; o >>= 1) v += __shfl_xor(v, o, 64);
  return v;
}
__device__ __forceinline__ float waveMax(float v) {
#pragma unroll
  for (int o = 32; o > 0; o >>= 1) v = fmaxf(v, __shfl_xor(v, o, 64));
  return v;
}
__device__ __forceinline__ float blockSum(float v, float* sh4) {
  v = waveSum(v);
  if ((threadIdx.x & 63) == 0) sh4[threadIdx.x >> 6] = v;
  __syncthreads();
  float r = sh4[0] + sh4[1] + sh4[2] + sh4[3];
  __syncthreads();
  return r;
}
__device__ __forceinline__ float blockMax(float v, float* sh4) {
  v = waveMax(v);
  if ((threadIdx.x & 63) == 0) sh4[threadIdx.x >> 6] = v;
  __syncthreads();
  float r = fmaxf(fmaxf(sh4[0], sh4[1]), fmaxf(sh4[2], sh4[3]));
  __syncthreads();
  return r;
}

// ---------------------------------------------------------------------------
__global__ void detect_kernel(const void* __restrict__ ln1g, int* __restrict__ flag) {
  unsigned u = *(const unsigned*)ln1g;
  *flag = (u == 0x3F800000u) ? 0 : 1;
}

// ---------------------------------------------------------------------------
// Transpose + ->bf16: src elements [eoff + k*N + n] -> dst[n*K + k].
// ---------------------------------------------------------------------------
__global__ __launch_bounds__(256) void transpose_kernel(const void* __restrict__ src,
                                                        u16* __restrict__ dst,
                                                        int K, int N, size_t eoff,
                                                        const int* __restrict__ F) {
  const int isb = *F;
  __shared__ u16 tile[32][33];
  int bx = blockIdx.x, by = blockIdx.y;
  int tx = threadIdx.x & 31, ty = threadIdx.x >> 5;
  for (int i = ty; i < 32; i += 8)
    tile[i][tx] = f2bf(ldf(src, eoff + (size_t)(by * 32 + i) * N + bx * 32 + tx, isb));
  __syncthreads();
  for (int i = ty; i < 32; i += 8)
    dst[(size_t)(bx * 32 + i) * K + by * 32 + tx] = tile[tx][i];
}

// ---------------------------------------------------------------------------
// Embedding + positional encoding. One block per token.
// ---------------------------------------------------------------------------
__global__ __launch_bounds__(256) void embed_kernel(const int* __restrict__ ids,
                                                    const void* __restrict__ emb,
                                                    u16* __restrict__ x, int L,
                                                    const int* __restrict__ F) {
  const int isb = *F;
  int tok = blockIdx.x;
  int pos = tok % L;
  int id = ids[tok];
  const float LOG1E4_OVER_D = 9.210340371976184f / 512.0f;
  for (int d = threadIdx.x; d < 512; d += 256) {
    float e = ldf(emb, (size_t)id * 512 + d, isb) * 22.62741699796952f;
    int i2 = d & ~1;
    float ang = (float)pos * expf(-(float)i2 * LOG1E4_OVER_D);
    float pe = (d & 1) ? cosf(ang) : sinf(ang);
    x[(size_t)tok * 512 + d] = f2bf(e + pe);
  }
}

// ---------------------------------------------------------------------------
// GEMM: C[M][N] = A[M][K] @ Bt[N][K]^T + bias[boff..]  (optional relu)
// bf16 in, fp32 MFMA accumulate, bf16 out. 128x128 tile, BK=64, 256 threads.
// ---------------------------------------------------------------------------
template <int RELU>
__global__ __launch_bounds__(256, 2) void gemm_bt(const u16* __restrict__ A,
                                                  const u16* __restrict__ Bt,
                                                  const void* __restrict__ bias,
                                                  u16* __restrict__ C,
                                                  int M, int N, int K, size_t boff,
                                                  const int* __restrict__ F) {
  const int isb = *F;
  __shared__ __align__(16) u16 As[128 * 64];
  __shared__ __align__(16) u16 Bs[128 * 64];
  const int tid = threadIdx.x;
  const int lane = tid & 63;
  const int wave = tid >> 6;
  const int wm = wave >> 1, wn = wave & 1;
  const int l15 = lane & 15, quad = lane >> 4;
  const int bm = blockIdx.y, bn = blockIdx.x;

  floatx4 acc[4][4];
#pragma unroll
  for (int i = 0; i < 4; i++)
#pragma unroll
    for (int j = 0; j < 4; j++) acc[i][j] = (floatx4){0.f, 0.f, 0.f, 0.f};

  const u16* Abase = A + (size_t)bm * 128 * K;
  const u16* Bbase = Bt + (size_t)bn * 128 * K;

  for (int kt = 0; kt < K; kt += 64) {
#pragma unroll
    for (int i = 0; i < 4; i++) {
      int c = i * 256 + tid;             // 0..1023 16B chunks
      int row = c >> 3, col = (c & 7) * 8;
      const u16* ga = &Abase[(size_t)row * K + kt + col];
      const u16* gb = &Bbase[(size_t)row * K + kt + col];
#ifdef USE_GLL
      __builtin_amdgcn_global_load_lds(
          (const __attribute__((address_space(1))) void*)ga,
          (__attribute__((address_space(3))) void*)&As[c * 8], 16, 0, 0);
      __builtin_amdgcn_global_load_lds(
          (const __attribute__((address_space(1))) void*)gb,
          (__attribute__((address_space(3))) void*)&Bs[c * 8], 16, 0, 0);
#else
      *(uint4*)&As[c * 8] = *(const uint4*)ga;
      *(uint4*)&Bs[c * 8] = *(const uint4*)gb;
#endif
    }
    __syncthreads();
#pragma unroll
    for (int ks = 0; ks < 2; ks++) {
      bf16x8 af[4], bfr[4];
#pragma unroll
      for (int mi = 0; mi < 4; mi++)
        af[mi] = *(const bf16x8*)&As[(wm * 64 + mi * 16 + l15) * 64 + ks * 32 + quad * 8];
#pragma unroll
      for (int ni = 0; ni < 4; ni++)
        bfr[ni] = *(const bf16x8*)&Bs[(wn * 64 + ni * 16 + l15) * 64 + ks * 32 + quad * 8];
#pragma unroll
      for (int mi = 0; mi < 4; mi++)
#pragma unroll
        for (int ni = 0; ni < 4; ni++)
          acc[mi][ni] = __builtin_amdgcn_mfma_f32_16x16x32_bf16(af[mi], bfr[ni], acc[mi][ni], 0, 0, 0);
    }
    __syncthreads();
  }

#pragma unroll
  for (int ni = 0; ni < 4; ni++) {
    int gcol = bn * 128 + wn * 64 + ni * 16 + l15;
    float bv = ldf(bias, boff + gcol, isb);
#pragma unroll
    for (int mi = 0; mi < 4; mi++) {
#pragma unroll
      for (int r = 0; r < 4; r++) {
        int grow = bm * 128 + wm * 64 + mi * 16 + quad * 4 + r;
        float v = acc[mi][ni][r] + bv;
        if (RELU) v = fmaxf(v, 0.f);
        C[(size_t)grow * N + gcol] = f2bf(v);
      }
    }
  }
}

// ---------------------------------------------------------------------------
// MFMA attention: one block per (seq, head), 256 threads (2x2 wave grid).
// qkv[M][1536]: q|k|v at col offsets 0/512/1024 + h*64.
// S = QK^T/8 (MFMA) -> fp32 softmax (4 thr/row) -> P bf16 (reuses Q LDS)
// -> O = P V (MFMA, V stored transposed). t >= L zero-filled; P[:, j>=L]=0
// and P rows >= L stay 0 (from zeroed Q), so L=32 needs no special paths.
// Fragment layouts (m89/m91): A/B [m|n=l&15][k=quad*8+j]; C/D row=quad*4+r,
// col=l&15.
// ---------------------------------------------------------------------------
__global__ __launch_bounds__(256) void attn_kernel(const u16* __restrict__ qkv,
                                                   u16* __restrict__ o, int L) {
  const int h = blockIdx.x & 7;
  const int s = blockIdx.x >> 3;
  __shared__ __align__(16) u16 Qs[64 * 72];   // Q, later reused as P
  __shared__ __align__(16) u16 Ks[64 * 72];
  __shared__ __align__(16) u16 Vt[64 * 72];   // V^T: [d][t]
  __shared__ float Ss[64 * 66];
  const int tid = threadIdx.x;
  const int lane = tid & 63;
  const int wave = tid >> 6;
  const int wm = wave >> 1, wn = wave & 1;
  const int l15 = lane & 15, quad = lane >> 4;
  const int base = s * L;

  // ---- stage Q, K (16B vector), V transposed; zero-fill t >= L ----
  for (int idx = tid; idx < 512; idx += 256) {   // 64 rows x 8 chunks of 8
    int t = idx >> 3, d8 = (idx & 7) * 8;
    if (t < L) {
      size_t g = (size_t)(base + t) * 1536 + h * 64 + d8;
      *(uint4*)&Qs[t * 72 + d8] = *(const uint4*)&qkv[g];
      *(uint4*)&Ks[t * 72 + d8] = *(const uint4*)&qkv[g + 512];
      u16 vv[8];
      *(uint4*)vv = *(const uint4*)&qkv[g + 1024];
#pragma unroll
      for (int i = 0; i < 8; i++) Vt[(d8 + i) * 72 + t] = vv[i];
    } else {
      uint4 z = {0u, 0u, 0u, 0u};
      *(uint4*)&Qs[t * 72 + d8] = z;
      *(uint4*)&Ks[t * 72 + d8] = z;
#pragma unroll
      for (int i = 0; i < 8; i++) Vt[(d8 + i) * 72 + t] = 0;
    }
  }
  __syncthreads();

  // ---- S = Q K^T * 0.125 : wave (wm,wn) -> 32x32 tile ----
  {
    floatx4 acc[2][2];
#pragma unroll
    for (int mi = 0; mi < 2; mi++)
#pragma unroll
      for (int ni = 0; ni < 2; ni++) acc[mi][ni] = (floatx4){0.f, 0.f, 0.f, 0.f};
#pragma unroll
    for (int ks = 0; ks < 2; ks++) {
      bf16x8 af[2], bfr[2];
#pragma unroll
      for (int mi = 0; mi < 2; mi++)
        af[mi] = *(const bf16x8*)&Qs[(wm * 32 + mi * 16 + l15) * 72 + ks * 32 + quad * 8];
#pragma unroll
      for (int ni = 0; ni < 2; ni++)
        bfr[ni] = *(const bf16x8*)&Ks[(wn * 32 + ni * 16 + l15) * 72 + ks * 32 + quad * 8];
#pragma unroll
      for (int mi = 0; mi < 2; mi++)
#pragma unroll
        for (int ni = 0; ni < 2; ni++)
          acc[mi][ni] = __builtin_amdgcn_mfma_f32_16x16x32_bf16(af[mi], bfr[ni], acc[mi][ni], 0, 0, 0);
    }
#pragma unroll
    for (int mi = 0; mi < 2; mi++)
#pragma unroll
      for (int ni = 0; ni < 2; ni++)
#pragma unroll
        for (int r = 0; r < 4; r++)
          Ss[(wm * 32 + mi * 16 + quad * 4 + r) * 66 + wn * 32 + ni * 16 + l15] =
              acc[mi][ni][r] * 0.125f;
  }
  __syncthreads();

  // ---- softmax rows (fp32), write P bf16 into Qs; cols >= L get 0 ----
  {
    int r = tid >> 2, sub = tid & 3;
    int j0 = sub * 16;
    float mx = -3.4e38f;
    if (r < L)
      for (int j = j0; j < j0 + 16; j++)
        if (j < L) mx = fmaxf(mx, Ss[r * 66 + j]);
    mx = fmaxf(mx, __shfl_xor(mx, 1, 64));
    mx = fmaxf(mx, __shfl_xor(mx, 2, 64));
    float sum = 0.f;
    if (r < L)
      for (int j = j0; j < j0 + 16; j++)
        if (j < L) sum += expf(Ss[r * 66 + j] - mx);
    sum += __shfl_xor(sum, 1, 64);
    sum += __shfl_xor(sum, 2, 64);
    float inv = 1.f / sum;
    if (r < L)
      for (int j = j0; j < j0 + 16; j++)
        Qs[r * 72 + j] = (j < L) ? f2bf(expf(Ss[r * 66 + j] - mx) * inv) : (u16)0;
  }
  __syncthreads();

  // ---- O = P V : wave (wm,wn) -> rows 32wm.., dims 32wn.. ----
  {
    floatx4 acc[2][2];
#pragma unroll
    for (int mi = 0; mi < 2; mi++)
#pragma unroll
      for (int ni = 0; ni < 2; ni++) acc[mi][ni] = (floatx4){0.f, 0.f, 0.f, 0.f};
#pragma unroll
    for (int ks = 0; ks < 2; ks++) {
      bf16x8 af[2], bfr[2];
#pragma unroll
      for (int mi = 0; mi < 2; mi++)
        af[mi] = *(const bf16x8*)&Qs[(wm * 32 + mi * 16 + l15) * 72 + ks * 32 + quad * 8];
#pragma unroll
      for (int ni = 0; ni < 2; ni++)
        bfr[ni] = *(const bf16x8*)&Vt[(wn * 32 + ni * 16 + l15) * 72 + ks * 32 + quad * 8];
#pragma unroll
      for (int mi = 0; mi < 2; mi++)
#pragma unroll
        for (int ni = 0; ni < 2; ni++)
          acc[mi][ni] = __builtin_amdgcn_mfma_f32_16x16x32_bf16(af[mi], bfr[ni], acc[mi][ni], 0, 0, 0);
    }
#pragma unroll
    for (int mi = 0; mi < 2; mi++) {
#pragma unroll
      for (int r = 0; r < 4; r++) {
        int t = wm * 32 + mi * 16 + quad * 4 + r;
        if (t < L) {
#pragma unroll
          for (int ni = 0; ni < 2; ni++) {
            int d = wn * 32 + ni * 16 + l15;
            o[(size_t)(base + t) * 512 + h * 64 + d] = f2bf(acc[mi][ni][r]);
          }
        }
      }
    }
  }
}

// ---------------------------------------------------------------------------
// x = LayerNorm(x + y) * g[eoff..] + b[eoff..]
// ---------------------------------------------------------------------------
__global__ __launch_bounds__(256) void add_ln_kernel(u16* __restrict__ x,
                                                     const u16* __restrict__ y,
                                                     const void* __restrict__ g,
                                                     const void* __restrict__ b,
                                                     size_t eoff,
                                                     const int* __restrict__ F) {
  const int isb = *F;
  const int row = blockIdx.x, tid = threadIdx.x;
  __shared__ float sh[4];
  size_t o0 = (size_t)row * 512 + tid;
  float v0 = bf2f(x[o0]) + bf2f(y[o0]);
  float v1 = bf2f(x[o0 + 256]) + bf2f(y[o0 + 256]);
  float mean = blockSum(v0 + v1, sh) * (1.f / 512.f);
  float d0 = v0 - mean, d1 = v1 - mean;
  float var = blockSum(d0 * d0 + d1 * d1, sh) * (1.f / 512.f);
  float rstd = rsqrtf(var + 1e-5f);
  x[o0]       = f2bf(d0 * rstd * ldf(g, eoff + tid, isb)       + ldf(b, eoff + tid, isb));
  x[o0 + 256] = f2bf(d1 * rstd * ldf(g, eoff + tid + 256, isb) + ldf(b, eoff + tid + 256, isb));
}

// ---------------------------------------------------------------------------
// Masked mean pool; mask elements at [moff + s*L + t].
// ---------------------------------------------------------------------------
__global__ __launch_bounds__(256) void pool_kernel(const u16* __restrict__ x,
                                                   const void* __restrict__ mask,
                                                   float* __restrict__ pooled, int L,
                                                   size_t moff,
                                                   const int* __restrict__ F) {
  const int isb = *F;
  const int s = blockIdx.x;
  float msum = 0.f;
  for (int t = 0; t < L; t++) msum += ldf(mask, moff + s * L + t, isb);
  float inv = 1.f / fmaxf(msum, 1e-9f);
  for (int d = threadIdx.x; d < 512; d += 256) {
    float acc = 0.f;
    for (int t = 0; t < L; t++)
      acc += bf2f(x[(size_t)(s * L + t) * 512 + d]) * ldf(mask, moff + s * L + t, isb);
    pooled[(size_t)s * 512 + d] = acc * inv;
  }
}

// ---------------------------------------------------------------------------
// Pairwise score
// ---------------------------------------------------------------------------
__global__ __launch_bounds__(64) void pair_score_kernel(const float* __restrict__ X,
                                                        const float* __restrict__ Y,
                                                        const void* __restrict__ Wv,
                                                        const void* __restrict__ bscal,
                                                        float* __restrict__ outp,
                                                        int NI, int NJ,
                                                        const int* __restrict__ F) {
  const int isb = *F;
  int gid = blockIdx.x;
  int j = gid % NJ;
  int t = gid / NJ;
  int i = t % NI;
  int b = t / NI;
  const float* xv = X + ((size_t)b * NI + i) * 512;
  const float* yv = Y + ((size_t)b * NJ + j) * 512;
  int l = threadIdx.x;
  float p = 0.f;
  for (int d = l; d < 512; d += 64) {
    float xi = xv[d], yj = yv[d];
    p += ldf(Wv, d, isb) * yj + ldf(Wv, 512 + d, isb) * xi +
         ldf(Wv, 1024 + d, isb) * fabsf(yj - xi) + ldf(Wv, 1536 + d, isb) * xi * yj;
  }
  p = waveSum(p);
  if (l == 0) outp[gid] = p + ldf(bscal, 0, isb);
}

__global__ __launch_bounds__(256) void aa_softmax_kernel(const float* __restrict__ aa,
                                                         float* __restrict__ aasm) {
  const int b = blockIdx.x;
  const float* src = aa + (size_t)b * 900;
  float* dst = aasm + (size_t)b * 900;
  __shared__ float sh[4];
  int tid = threadIdx.x;
  float mx = -3.4e38f;
  for (int i = tid; i < 900; i += 256) mx = fmaxf(mx, src[i]);
  mx = blockMax(mx, sh);
  float sum = 0.f;
  for (int i = tid; i < 900; i += 256) sum += expf(src[i] - mx);
  sum = blockSum(sum, sh);
  float inv = 1.f / sum;
  for (int i = tid; i < 900; i += 256) {
    int r = i / 30, c = i - r * 30;
    dst[i] = (r == c) ? 0.f : expf(src[i] - mx) * inv;
  }
}

__global__ __launch_bounds__(64) void qa_softmax_kernel(const float* __restrict__ qa,
                                                        float* __restrict__ sim) {
  int g = blockIdx.x;
  int l = threadIdx.x;
  float v = (l < 30) ? qa[(size_t)g * 30 + l] : -3.4e38f;
  float mx = waveMax(v);
  float e = (l < 30) ? expf(v - mx) : 0.f;
  float s = waveSum(e);
  if (l < 30) sim[(size_t)g * 30 + l] = e / s;
}

// ---------------------------------------------------------------------------
// Edge weights
// ---------------------------------------------------------------------------
__global__ __launch_bounds__(256) void edgew_kernel(const void* __restrict__ aaov,
                                                    const void* __restrict__ aasim_in,
                                                    const void* __restrict__ qaov,
                                                    const void* __restrict__ qq,
                                                    const float* __restrict__ aasm,
                                                    const float* __restrict__ sim,
                                                    const void* __restrict__ p1,
                                                    const void* __restrict__ p2,
                                                    const void* __restrict__ p3,
                                                    const void* __restrict__ p4,
                                                    float* __restrict__ Wout,
                                                    const int* __restrict__ F) {
  const int isb = *F;
  int e = blockIdx.x * 256 + threadIdx.x;
  if (e >= 16 * 1156) return;
  int b = e / 1156;
  int rem = e - b * 1156;
  int r = rem / 34, c = rem - r * 34;
  float aas;
  if (r >= 4 && c >= 4) aas = aasm[(size_t)b * 900 + (r - 4) * 30 + (c - 4)];
  else                  aas = ldf(aasim_in, e, isb);
  float qas = 0.f;
  if (r >= 4 && c < 4)      qas = sim[((size_t)b * 4 + c) * 30 + (r - 4)];
  else if (r < 4 && c >= 4) qas = sim[((size_t)b * 4 + r) * 30 + (c - 4)];
  float w = -ldf(p1, 0, isb) * ldf(aaov, e, isb) + ldf(p2, 0, isb) * aas +
            ldf(p3, 0, isb) * ldf(qaov, e, isb) + ldf(p4, 0, isb) * qas +
            ldf(qq, e, isb);
  Wout[e] = w;
}

// ---------------------------------------------------------------------------
// Projected gradient ascent (100 iters), register-resident, barrier-free.
// ---------------------------------------------------------------------------
__global__ __launch_bounds__(64) void solve_kernel(const float* __restrict__ Wmat,
                                                   float* __restrict__ pred,
                                                   float* __restrict__ outp) {
  const int b = blockIdx.x;
  const int lane = threadIdx.x;
  float E[19], Ws[19], As[19];
  bool dg[19];
#pragma unroll
  for (int k = 0; k < 19; k++) {
    int e = lane + (k << 6);
    if (e < 1156) {
      int r = e / 34, c = e - r * 34;
      float w1 = Wmat[(size_t)b * 1156 + e];
      float w2 = Wmat[(size_t)b * 1156 + c * 34 + r];
      Ws[k] = 0.5f * (w1 + w2);
      As[k] = 0.5f * (((w1 != 0.f) ? 1.f : 0.f) + ((w2 != 0.f) ? 1.f : 0.f));
      dg[k] = (r == c && r < 4);
      E[k] = 0.5f;
    } else {
      Ws[k] = 0.f; As[k] = 0.f; dg[k] = false; E[k] = 0.f;
    }
  }
  for (int it = 0; it < 100; it++) {
    float ps = 0.f;
#pragma unroll
    for (int k = 0; k < 19; k++) ps += As[k] * E[k];
    float s = waveSum(ps);
    float dd = __shfl(E[0], 0, 64) + __shfl(E[0], 35, 64) +
               __shfl(E[1], 6, 64) + __shfl(E[1], 41, 64);
    float coef_s = (s > 6.f) ? 20.f * (s - 6.f) : 0.f;
    float coef_d = 20.f * (dd - 1.f);
#pragma unroll
    for (int k = 0; k < 19; k++) {
      float g = Ws[k] - coef_s * As[k] - (dg[k] ? coef_d : 0.f);
      E[k] = fminf(fmaxf(E[k] + 0.05f * g, 0.f), 1.f);
    }
  }
  float v0 = E[0], v1 = E[1];
  if (lane == 0)  { pred[b * 4 + 0] = v0; outp[1 + b * 4 + 0] = v0; }
  if (lane == 35) { pred[b * 4 + 1] = v0; outp[1 + b * 4 + 1] = v0; }
  if (lane == 6)  { pred[b * 4 + 2] = v1; outp[1 + b * 4 + 2] = v1; }
  if (lane == 41) { pred[b * 4 + 3] = v1; outp[1 + b * 4 + 3] = v1; }
}

// ---------------------------------------------------------------------------
// Final loss: out[0] = ce(log_softmax(pred), labels) + mse(sim, gold_sm)
// ---------------------------------------------------------------------------
__global__ __launch_bounds__(256) void loss_kernel(const float* __restrict__ sim,
                                                   const void* __restrict__ gold,
                                                   const float* __restrict__ pred,
                                                   const int* __restrict__ labels,
                                                   float* __restrict__ outp,
                                                   const int* __restrict__ F) {
  const int isb = *F;
  __shared__ float sh[4];
  const int tid = threadIdx.x;
  float local = 0.f;
  if (tid < 64) {
    float mx = -3.4e38f;
    for (int k = 0; k < 30; k++) mx = fmaxf(mx, ldf(gold, (size_t)tid * 30 + k, isb));
    float sum = 0.f;
    for (int k = 0; k < 30; k++) sum += expf(ldf(gold, (size_t)tid * 30 + k, isb) - mx);
    float inv = 1.f / sum;
    for (int k = 0; k < 30; k++) {
      float gsm = expf(ldf(gold, (size_t)tid * 30 + k, isb) - mx) * inv;
      float d = sim[(size_t)tid * 30 + k] - gsm;
      local += d * d;
    }
  }
  float mse = blockSum(local, sh) * (1.f / 1920.f);
  float cel = 0.f;
  if (tid < 16) {
    const float* f = pred + tid * 4;
    int lb = labels[tid] & 3;
    float mx = fmaxf(fmaxf(f[0], f[1]), fmaxf(f[2], f[3]));
    float lse = logf(expf(f[0] - mx) + expf(f[1] - mx) + expf(f[2] - mx) + expf(f[3] - mx));
    float lp = f[lb] - mx - lse;
    cel = -lp * (1.f / 16.f);
  }
  float ce = blockSum(cel, sh);
  if (tid == 0) outp[0] = ce + mse;
}

// ---------------------------------------------------------------------------
// Host orchestration
// ---------------------------------------------------------------------------
extern "C" void kernel_launch(void* const* d_in, const int* in_sizes, int n_in,
                              void* d_out, int out_size, void* d_ws, size_t ws_size,
                              hipStream_t stream) {
  (void)in_sizes; (void)n_in; (void)out_size;
  const int*  hyp_ids   = (const int*)d_in[0];
  const void* hyp_mask  = d_in[1];
  const void* fact_mask = d_in[2];
  const int*  fact_ids  = (const int*)d_in[3];
  const void* aa_ov     = d_in[5];
  const void* aa_sim_in = d_in[6];
  const void* qa_ov     = d_in[8];
  const void* qq        = d_in[11];
  const int*  labels    = (const int*)d_in[12];
  const void* gold      = d_in[13];
  const void* emb       = d_in[14];
  const void* Wqkv      = d_in[15];
  const void* bqkv      = d_in[16];
  const void* Wo        = d_in[17];
  const void* bo        = d_in[18];
  const void* ln1g      = d_in[19];
  const void* ln1b      = d_in[20];
  const void* Wff1      = d_in[21];
  const void* bff1      = d_in[22];
  const void* Wff2      = d_in[23];
  const void* bff2      = d_in[24];
  const void* ln2g      = d_in[25];
  const void* ln2b      = d_in[26];
  const void* scoreW    = d_in[27];
  const void* scoreB    = d_in[28];
  const void* absW      = d_in[29];
  const void* absB      = d_in[30];
  const void* p_aaov    = d_in[31];
  const void* p_aasim   = d_in[32];
  const void* p_qaov    = d_in[33];
  const void* p_qasim   = d_in[34];
  float* out = (float*)d_out;

  char* ws = (char*)d_ws;
  size_t off = 0;
  auto alloc = [&](size_t bytes) -> void* {
    void* p = ws + off;
    off += (bytes + 255) & ~(size_t)255;
    return p;
  };

  float* PRED = (float*)alloc(64ull * 4);
  int*   FLAG = (int*)alloc(256);
  float* SIM  = (float*)alloc(16ull * 120 * 4);
  float* QA   = (float*)alloc(16ull * 120 * 4);
  float* AASM = (float*)alloc(16ull * 900 * 4);
  float* AA   = (float*)alloc(16ull * 900 * 4);
  float* WMAT = (float*)alloc(16ull * 1156 * 4);
  float* FSEQ = (float*)alloc(480ull * 512 * 4);
  float* HSEQ = (float*)alloc(64ull * 512 * 4);
  u16* WT_QKV = (u16*)alloc(2ull * 1536 * 512 * 2);
  u16* WT_O   = (u16*)alloc(2ull * 512 * 512 * 2);
  u16* WT_F1  = (u16*)alloc(2ull * 2048 * 512 * 2);
  u16* WT_F2  = (u16*)alloc(2ull * 512 * 2048 * 2);

  // Dynamic chunking from ws_size (constant per process -> graph-safe).
  const int opts_tok[5] = {30720, 15360, 10240, 6144, 3072};
  const int opts_nch[5] = {1, 2, 3, 5, 10};
  int CH_TOK = 3072, NCH = 10;
  for (int i = 0; i < 5; i++) {
    size_t need = off + (size_t)opts_tok[i] * 7168 + 4096;
    if (need <= ws_size) { CH_TOK = opts_tok[i]; NCH = opts_nch[i]; break; }
  }
  u16* X   = (u16*)alloc((size_t)CH_TOK * 512 * 2);
  u16* BIG = (u16*)alloc((size_t)CH_TOK * 2048 * 2);
  u16* ATT = (u16*)alloc((size_t)CH_TOK * 512 * 2);
  u16* Y   = (u16*)alloc((size_t)CH_TOK * 512 * 2);

  detect_kernel<<<1, 1, 0, stream>>>(ln1g, FLAG);

  for (int l = 0; l < 2; l++) {
    transpose_kernel<<<dim3(48, 16), 256, 0, stream>>>(
        Wqkv, WT_QKV + (size_t)l * 1536 * 512, 512, 1536, (size_t)l * 512 * 1536, FLAG);
    transpose_kernel<<<dim3(16, 16), 256, 0, stream>>>(
        Wo, WT_O + (size_t)l * 512 * 512, 512, 512, (size_t)l * 512 * 512, FLAG);
    transpose_kernel<<<dim3(64, 16), 256, 0, stream>>>(
        Wff1, WT_F1 + (size_t)l * 2048 * 512, 512, 2048, (size_t)l * 512 * 2048, FLAG);
    transpose_kernel<<<dim3(16, 64), 256, 0, stream>>>(
        Wff2, WT_F2 + (size_t)l * 512 * 2048, 2048, 512, (size_t)l * 2048 * 512, FLAG);
  }

  auto encode = [&](const int* ids, int nseq, int L, const void* mask,
                    size_t moff, float* pooled) {
    int M = nseq * L;   // multiple of 128
    embed_kernel<<<M, 256, 0, stream>>>(ids, emb, X, L, FLAG);
    for (int l = 0; l < 2; l++) {
      gemm_bt<0><<<dim3(12, M / 128), 256, 0, stream>>>(
          X, WT_QKV + (size_t)l * 1536 * 512, bqkv, BIG, M, 1536, 512,
          (size_t)l * 1536, FLAG);
      attn_kernel<<<nseq * 8, 256, 0, stream>>>(BIG, ATT, L);
      gemm_bt<0><<<dim3(4, M / 128), 256, 0, stream>>>(
          ATT, WT_O + (size_t)l * 512 * 512, bo, Y, M, 512, 512,
          (size_t)l * 512, FLAG);
      add_ln_kernel<<<M, 256, 0, stream>>>(X, Y, ln1g, ln1b, (size_t)l * 512, FLAG);
      gemm_bt<1><<<dim3(16, M / 128), 256, 0, stream>>>(
          X, WT_F1 + (size_t)l * 2048 * 512, bff1, BIG, M, 2048, 512,
          (size_t)l * 2048, FLAG);
      gemm_bt<0><<<dim3(4, M / 128), 256, 0, stream>>>(
          BIG, WT_F2 + (size_t)l * 512 * 2048, bff2, Y, M, 512, 2048,
          (size_t)l * 512, FLAG);
      add_ln_kernel<<<M, 256, 0, stream>>>(X, Y, ln2g, ln2b, (size_t)l * 512, FLAG);
    }
    pool_kernel<<<nseq, 256, 0, stream>>>(X, mask, pooled, L, moff, FLAG);
  };

  const int seq_per = 480 / NCH;
  for (int c = 0; c < NCH; c++) {
    encode(fact_ids + (size_t)c * seq_per * 64, seq_per, 64, fact_mask,
           (size_t)c * seq_per * 64, FSEQ + (size_t)c * seq_per * 512);
  }
  encode(hyp_ids, 64, 32, hyp_mask, 0, HSEQ);

  pair_score_kernel<<<16 * 30 * 30, 64, 0, stream>>>(FSEQ, FSEQ, absW, absB, AA, 30, 30, FLAG);
  pair_score_kernel<<<16 * 4 * 30, 64, 0, stream>>>(HSEQ, FSEQ, scoreW, scoreB, QA, 4, 30, FLAG);
  aa_softmax_kernel<<<16, 256, 0, stream>>>(AA, AASM);
  qa_softmax_kernel<<<64, 64, 0, stream>>>(QA, SIM);

  edgew_kernel<<<(16 * 1156 + 255) / 256, 256, 0, stream>>>(
      aa_ov, aa_sim_in, qa_ov, qq, AASM, SIM, p_aaov, p_aasim, p_qaov, p_qasim,
      WMAT, FLAG);
  solve_kernel<<<16, 64, 0, stream>>>(WMAT, PRED, out);
  loss_kernel<<<1, 256, 0, stream>>>(SIM, gold, PRED, labels, out, FLAG);
}

// Round 8
// 1248.520 us; speedup vs baseline: 3.3253x; 1.0836x over previous
//
#include <hip/hip_runtime.h>
#include <cstdint>
#include <cstddef>

// ---------------------------------------------------------------------------
// B=16 V=30522 D=512 H=8 DH=64 FF=2048 NC=4 NF=30 NN=34 FL=64 HL=32 L=2
// INPUT float tensors may be fp32 OR bf16 -- detected at runtime from ln1_g
// (all 1.0): fp32 -> first u32 == 0x3F800000 ; bf16 -> 0x3F803F80.
// OUTPUT: 65 FLOAT32 values = [loss, final_pred(16x4)].
// R8 change vs R7 (passed, 1353 us): GEMM LDS bank-conflict fix. R7 profile:
// top GEMMs had SQ_LDS_BANK_CONFLICT=2.36e7 (~12 cyc/ds_read_b128) because
// row stride 128 B == 32 banks -> 16-way conflicts on fragment reads.
// Fix: rotate 16B chunks within each row (pos = (chunk + row) & 7). Staging
// keeps lane-contiguous LDS dests (global_load_lds constraint) by rotating
// the GLOBAL chunk each lane fetches (same 128B line -> coalescing intact).
// ---------------------------------------------------------------------------

using u16 = unsigned short;

typedef __bf16 bf16x8 __attribute__((ext_vector_type(8)));
typedef float  floatx4 __attribute__((ext_vector_type(4)));

#if defined(__has_builtin)
#if __has_builtin(__builtin_amdgcn_global_load_lds)
#define USE_GLL 1
#endif
#endif

__device__ __forceinline__ float bf2f(u16 u) {
  return __uint_as_float(((unsigned)u) << 16);
}
__device__ __forceinline__ u16 f2bf(float f) {
  unsigned u = __float_as_uint(f);
  u += 0x7FFFu + ((u >> 16) & 1u);   // round-to-nearest-even
  return (u16)(u >> 16);
}
__device__ __forceinline__ float ldf(const void* p, size_t i, int isb) {
  return isb ? bf2f(((const u16*)p)[i]) : ((const float*)p)[i];
}

__device__ __forceinline__ float waveSum(float v) {
#pragma unroll
  for (int o = 32; o > 0; o >>= 1) v += __shfl_xor(v, o, 64);
  return v;
}
__device__ __forceinline__ float waveMax(float v) {
#pragma unroll
  for (int o = 32; o > 0; o >>= 1) v = fmaxf(v, __shfl_xor(v, o, 64));
  return v;
}
__device__ __forceinline__ float blockSum(float v, float* sh4) {
  v = waveSum(v);
  if ((threadIdx.x & 63) == 0) sh4[threadIdx.x >> 6] = v;
  __syncthreads();
  float r = sh4[0] + sh4[1] + sh4[2] + sh4[3];
  __syncthreads();
  return r;
}
__device__ __forceinline__ float blockMax(float v, float* sh4) {
  v = waveMax(v);
  if ((threadIdx.x & 63) == 0) sh4[threadIdx.x >> 6] = v;
  __syncthreads();
  float r = fmaxf(fmaxf(sh4[0], sh4[1]), fmaxf(sh4[2], sh4[3]));
  __syncthreads();
  return r;
}

// ---------------------------------------------------------------------------
__global__ void detect_kernel(const void* __restrict__ ln1g, int* __restrict__ flag) {
  unsigned u = *(const unsigned*)ln1g;
  *flag = (u == 0x3F800000u) ? 0 : 1;
}

// ---------------------------------------------------------------------------
// Transpose + ->bf16: src elements [eoff + k*N + n] -> dst[n*K + k].
// ---------------------------------------------------------------------------
__global__ __launch_bounds__(256) void transpose_kernel(const void* __restrict__ src,
                                                        u16* __restrict__ dst,
                                                        int K, int N, size_t eoff,
                                                        const int* __restrict__ F) {
  const int isb = *F;
  __shared__ u16 tile[32][33];
  int bx = blockIdx.x, by = blockIdx.y;
  int tx = threadIdx.x & 31, ty = threadIdx.x >> 5;
  for (int i = ty; i < 32; i += 8)
    tile[i][tx] = f2bf(ldf(src, eoff + (size_t)(by * 32 + i) * N + bx * 32 + tx, isb));
  __syncthreads();
  for (int i = ty; i < 32; i += 8)
    dst[(size_t)(bx * 32 + i) * K + by * 32 + tx] = tile[tx][i];
}

// ---------------------------------------------------------------------------
// Embedding + positional encoding. One block per token.
// ---------------------------------------------------------------------------
__global__ __launch_bounds__(256) void embed_kernel(const int* __restrict__ ids,
                                                    const void* __restrict__ emb,
                                                    u16* __restrict__ x, int L,
                                                    const int* __restrict__ F) {
  const int isb = *F;
  int tok = blockIdx.x;
  int pos = tok % L;
  int id = ids[tok];
  const float LOG1E4_OVER_D = 9.210340371976184f / 512.0f;
  for (int d = threadIdx.x; d < 512; d += 256) {
    float e = ldf(emb, (size_t)id * 512 + d, isb) * 22.62741699796952f;
    int i2 = d & ~1;
    float ang = (float)pos * expf(-(float)i2 * LOG1E4_OVER_D);
    float pe = (d & 1) ? cosf(ang) : sinf(ang);
    x[(size_t)tok * 512 + d] = f2bf(e + pe);
  }
}

// ---------------------------------------------------------------------------
// GEMM: C[M][N] = A[M][K] @ Bt[N][K]^T + bias[boff..]  (optional relu)
// bf16 in, fp32 MFMA accumulate, bf16 out. 128x128 tile, BK=64, 256 threads.
// LDS layout: row r holds its eight 16B chunks ROTATED: global chunk q at
// position (q + r) & 7. Fragment reads (16 lanes, consecutive rows, same q)
// then spread over all 32 banks (2-way = free) instead of 16-way conflicts.
// ---------------------------------------------------------------------------
template <int RELU>
__global__ __launch_bounds__(256, 2) void gemm_bt(const u16* __restrict__ A,
                                                  const u16* __restrict__ Bt,
                                                  const void* __restrict__ bias,
                                                  u16* __restrict__ C,
                                                  int M, int N, int K, size_t boff,
                                                  const int* __restrict__ F) {
  const int isb = *F;
  __shared__ __align__(16) u16 As[128 * 64];
  __shared__ __align__(16) u16 Bs[128 * 64];
  const int tid = threadIdx.x;
  const int lane = tid & 63;
  const int wave = tid >> 6;
  const int wm = wave >> 1, wn = wave & 1;
  const int l15 = lane & 15, quad = lane >> 4;
  const int bm = blockIdx.y, bn = blockIdx.x;

  floatx4 acc[4][4];
#pragma unroll
  for (int i = 0; i < 4; i++)
#pragma unroll
    for (int j = 0; j < 4; j++) acc[i][j] = (floatx4){0.f, 0.f, 0.f, 0.f};

  const u16* Abase = A + (size_t)bm * 128 * K;
  const u16* Bbase = Bt + (size_t)bn * 128 * K;

  for (int kt = 0; kt < K; kt += 64) {
#pragma unroll
    for (int i = 0; i < 4; i++) {
      int c = i * 256 + tid;             // LDS chunk id 0..1023 (lane-contig)
      int row = c >> 3, p = c & 7;
      int col = (((p - row) & 7)) * 8;   // rotated source chunk (same 128B line)
      const u16* ga = &Abase[(size_t)row * K + kt + col];
      const u16* gb = &Bbase[(size_t)row * K + kt + col];
#ifdef USE_GLL
      __builtin_amdgcn_global_load_lds(
          (const __attribute__((address_space(1))) void*)ga,
          (__attribute__((address_space(3))) void*)&As[c * 8], 16, 0, 0);
      __builtin_amdgcn_global_load_lds(
          (const __attribute__((address_space(1))) void*)gb,
          (__attribute__((address_space(3))) void*)&Bs[c * 8], 16, 0, 0);
#else
      *(uint4*)&As[c * 8] = *(const uint4*)ga;
      *(uint4*)&Bs[c * 8] = *(const uint4*)gb;
#endif
    }
    __syncthreads();
#pragma unroll
    for (int ks = 0; ks < 2; ks++) {
      bf16x8 af[4], bfr[4];
#pragma unroll
      for (int mi = 0; mi < 4; mi++) {
        int ra = wm * 64 + mi * 16 + l15;
        int q = ks * 4 + quad;
        af[mi] = *(const bf16x8*)&As[ra * 64 + ((q + ra) & 7) * 8];
      }
#pragma unroll
      for (int ni = 0; ni < 4; ni++) {
        int rb = wn * 64 + ni * 16 + l15;
        int q = ks * 4 + quad;
        bfr[ni] = *(const bf16x8*)&Bs[rb * 64 + ((q + rb) & 7) * 8];
      }
#pragma unroll
      for (int mi = 0; mi < 4; mi++)
#pragma unroll
        for (int ni = 0; ni < 4; ni++)
          acc[mi][ni] = __builtin_amdgcn_mfma_f32_16x16x32_bf16(af[mi], bfr[ni], acc[mi][ni], 0, 0, 0);
    }
    __syncthreads();
  }

#pragma unroll
  for (int ni = 0; ni < 4; ni++) {
    int gcol = bn * 128 + wn * 64 + ni * 16 + l15;
    float bv = ldf(bias, boff + gcol, isb);
#pragma unroll
    for (int mi = 0; mi < 4; mi++) {
#pragma unroll
      for (int r = 0; r < 4; r++) {
        int grow = bm * 128 + wm * 64 + mi * 16 + quad * 4 + r;
        float v = acc[mi][ni][r] + bv;
        if (RELU) v = fmaxf(v, 0.f);
        C[(size_t)grow * N + gcol] = f2bf(v);
      }
    }
  }
}

// ---------------------------------------------------------------------------
// MFMA attention: one block per (seq, head), 256 threads (2x2 wave grid).
// LDS row stride 72 elems (144 B) -> fragment reads are 2-way (free).
// ---------------------------------------------------------------------------
__global__ __launch_bounds__(256) void attn_kernel(const u16* __restrict__ qkv,
                                                   u16* __restrict__ o, int L) {
  const int h = blockIdx.x & 7;
  const int s = blockIdx.x >> 3;
  __shared__ __align__(16) u16 Qs[64 * 72];   // Q, later reused as P
  __shared__ __align__(16) u16 Ks[64 * 72];
  __shared__ __align__(16) u16 Vt[64 * 72];   // V^T: [d][t]
  __shared__ float Ss[64 * 66];
  const int tid = threadIdx.x;
  const int lane = tid & 63;
  const int wave = tid >> 6;
  const int wm = wave >> 1, wn = wave & 1;
  const int l15 = lane & 15, quad = lane >> 4;
  const int base = s * L;

  for (int idx = tid; idx < 512; idx += 256) {
    int t = idx >> 3, d8 = (idx & 7) * 8;
    if (t < L) {
      size_t g = (size_t)(base + t) * 1536 + h * 64 + d8;
      *(uint4*)&Qs[t * 72 + d8] = *(const uint4*)&qkv[g];
      *(uint4*)&Ks[t * 72 + d8] = *(const uint4*)&qkv[g + 512];
      u16 vv[8];
      *(uint4*)vv = *(const uint4*)&qkv[g + 1024];
#pragma unroll
      for (int i = 0; i < 8; i++) Vt[(d8 + i) * 72 + t] = vv[i];
    } else {
      uint4 z = {0u, 0u, 0u, 0u};
      *(uint4*)&Qs[t * 72 + d8] = z;
      *(uint4*)&Ks[t * 72 + d8] = z;
#pragma unroll
      for (int i = 0; i < 8; i++) Vt[(d8 + i) * 72 + t] = 0;
    }
  }
  __syncthreads();

  {
    floatx4 acc[2][2];
#pragma unroll
    for (int mi = 0; mi < 2; mi++)
#pragma unroll
      for (int ni = 0; ni < 2; ni++) acc[mi][ni] = (floatx4){0.f, 0.f, 0.f, 0.f};
#pragma unroll
    for (int ks = 0; ks < 2; ks++) {
      bf16x8 af[2], bfr[2];
#pragma unroll
      for (int mi = 0; mi < 2; mi++)
        af[mi] = *(const bf16x8*)&Qs[(wm * 32 + mi * 16 + l15) * 72 + ks * 32 + quad * 8];
#pragma unroll
      for (int ni = 0; ni < 2; ni++)
        bfr[ni] = *(const bf16x8*)&Ks[(wn * 32 + ni * 16 + l15) * 72 + ks * 32 + quad * 8];
#pragma unroll
      for (int mi = 0; mi < 2; mi++)
#pragma unroll
        for (int ni = 0; ni < 2; ni++)
          acc[mi][ni] = __builtin_amdgcn_mfma_f32_16x16x32_bf16(af[mi], bfr[ni], acc[mi][ni], 0, 0, 0);
    }
#pragma unroll
    for (int mi = 0; mi < 2; mi++)
#pragma unroll
      for (int ni = 0; ni < 2; ni++)
#pragma unroll
        for (int r = 0; r < 4; r++)
          Ss[(wm * 32 + mi * 16 + quad * 4 + r) * 66 + wn * 32 + ni * 16 + l15] =
              acc[mi][ni][r] * 0.125f;
  }
  __syncthreads();

  {
    int r = tid >> 2, sub = tid & 3;
    int j0 = sub * 16;
    float mx = -3.4e38f;
    if (r < L)
      for (int j = j0; j < j0 + 16; j++)
        if (j < L) mx = fmaxf(mx, Ss[r * 66 + j]);
    mx = fmaxf(mx, __shfl_xor(mx, 1, 64));
    mx = fmaxf(mx, __shfl_xor(mx, 2, 64));
    float sum = 0.f;
    if (r < L)
      for (int j = j0; j < j0 + 16; j++)
        if (j < L) sum += expf(Ss[r * 66 + j] - mx);
    sum += __shfl_xor(sum, 1, 64);
    sum += __shfl_xor(sum, 2, 64);
    float inv = 1.f / sum;
    if (r < L)
      for (int j = j0; j < j0 + 16; j++)
        Qs[r * 72 + j] = (j < L) ? f2bf(expf(Ss[r * 66 + j] - mx) * inv) : (u16)0;
  }
  __syncthreads();

  {
    floatx4 acc[2][2];
#pragma unroll
    for (int mi = 0; mi < 2; mi++)
#pragma unroll
      for (int ni = 0; ni < 2; ni++) acc[mi][ni] = (floatx4){0.f, 0.f, 0.f, 0.f};
#pragma unroll
    for (int ks = 0; ks < 2; ks++) {
      bf16x8 af[2], bfr[2];
#pragma unroll
      for (int mi = 0; mi < 2; mi++)
        af[mi] = *(const bf16x8*)&Qs[(wm * 32 + mi * 16 + l15) * 72 + ks * 32 + quad * 8];
#pragma unroll
      for (int ni = 0; ni < 2; ni++)
        bfr[ni] = *(const bf16x8*)&Vt[(wn * 32 + ni * 16 + l15) * 72 + ks * 32 + quad * 8];
#pragma unroll
      for (int mi = 0; mi < 2; mi++)
#pragma unroll
        for (int ni = 0; ni < 2; ni++)
          acc[mi][ni] = __builtin_amdgcn_mfma_f32_16x16x32_bf16(af[mi], bfr[ni], acc[mi][ni], 0, 0, 0);
    }
#pragma unroll
    for (int mi = 0; mi < 2; mi++) {
#pragma unroll
      for (int r = 0; r < 4; r++) {
        int t = wm * 32 + mi * 16 + quad * 4 + r;
        if (t < L) {
#pragma unroll
          for (int ni = 0; ni < 2; ni++) {
            int d = wn * 32 + ni * 16 + l15;
            o[(size_t)(base + t) * 512 + h * 64 + d] = f2bf(acc[mi][ni][r]);
          }
        }
      }
    }
  }
}

// ---------------------------------------------------------------------------
// x = LayerNorm(x + y) * g[eoff..] + b[eoff..]
// ---------------------------------------------------------------------------
__global__ __launch_bounds__(256) void add_ln_kernel(u16* __restrict__ x,
                                                     const u16* __restrict__ y,
                                                     const void* __restrict__ g,
                                                     const void* __restrict__ b,
                                                     size_t eoff,
                                                     const int* __restrict__ F) {
  const int isb = *F;
  const int row = blockIdx.x, tid = threadIdx.x;
  __shared__ float sh[4];
  size_t o0 = (size_t)row * 512 + tid;
  float v0 = bf2f(x[o0]) + bf2f(y[o0]);
  float v1 = bf2f(x[o0 + 256]) + bf2f(y[o0 + 256]);
  float mean = blockSum(v0 + v1, sh) * (1.f / 512.f);
  float d0 = v0 - mean, d1 = v1 - mean;
  float var = blockSum(d0 * d0 + d1 * d1, sh) * (1.f / 512.f);
  float rstd = rsqrtf(var + 1e-5f);
  x[o0]       = f2bf(d0 * rstd * ldf(g, eoff + tid, isb)       + ldf(b, eoff + tid, isb));
  x[o0 + 256] = f2bf(d1 * rstd * ldf(g, eoff + tid + 256, isb) + ldf(b, eoff + tid + 256, isb));
}

// ---------------------------------------------------------------------------
// Masked mean pool; mask elements at [moff + s*L + t].
// ---------------------------------------------------------------------------
__global__ __launch_bounds__(256) void pool_kernel(const u16* __restrict__ x,
                                                   const void* __restrict__ mask,
                                                   float* __restrict__ pooled, int L,
                                                   size_t moff,
                                                   const int* __restrict__ F) {
  const int isb = *F;
  const int s = blockIdx.x;
  float msum = 0.f;
  for (int t = 0; t < L; t++) msum += ldf(mask, moff + s * L + t, isb);
  float inv = 1.f / fmaxf(msum, 1e-9f);
  for (int d = threadIdx.x; d < 512; d += 256) {
    float acc = 0.f;
    for (int t = 0; t < L; t++)
      acc += bf2f(x[(size_t)(s * L + t) * 512 + d]) * ldf(mask, moff + s * L + t, isb);
    pooled[(size_t)s * 512 + d] = acc * inv;
  }
}

// ---------------------------------------------------------------------------
// Pairwise score
// ---------------------------------------------------------------------------
__global__ __launch_bounds__(64) void pair_score_kernel(const float* __restrict__ X,
                                                        const float* __restrict__ Y,
                                                        const void* __restrict__ Wv,
                                                        const void* __restrict__ bscal,
                                                        float* __restrict__ outp,
                                                        int NI, int NJ,
                                                        const int* __restrict__ F) {
  const int isb = *F;
  int gid = blockIdx.x;
  int j = gid % NJ;
  int t = gid / NJ;
  int i = t % NI;
  int b = t / NI;
  const float* xv = X + ((size_t)b * NI + i) * 512;
  const float* yv = Y + ((size_t)b * NJ + j) * 512;
  int l = threadIdx.x;
  float p = 0.f;
  for (int d = l; d < 512; d += 64) {
    float xi = xv[d], yj = yv[d];
    p += ldf(Wv, d, isb) * yj + ldf(Wv, 512 + d, isb) * xi +
         ldf(Wv, 1024 + d, isb) * fabsf(yj - xi) + ldf(Wv, 1536 + d, isb) * xi * yj;
  }
  p = waveSum(p);
  if (l == 0) outp[gid] = p + ldf(bscal, 0, isb);
}

__global__ __launch_bounds__(256) void aa_softmax_kernel(const float* __restrict__ aa,
                                                         float* __restrict__ aasm) {
  const int b = blockIdx.x;
  const float* src = aa + (size_t)b * 900;
  float* dst = aasm + (size_t)b * 900;
  __shared__ float sh[4];
  int tid = threadIdx.x;
  float mx = -3.4e38f;
  for (int i = tid; i < 900; i += 256) mx = fmaxf(mx, src[i]);
  mx = blockMax(mx, sh);
  float sum = 0.f;
  for (int i = tid; i < 900; i += 256) sum += expf(src[i] - mx);
  sum = blockSum(sum, sh);
  float inv = 1.f / sum;
  for (int i = tid; i < 900; i += 256) {
    int r = i / 30, c = i - r * 30;
    dst[i] = (r == c) ? 0.f : expf(src[i] - mx) * inv;
  }
}

__global__ __launch_bounds__(64) void qa_softmax_kernel(const float* __restrict__ qa,
                                                        float* __restrict__ sim) {
  int g = blockIdx.x;
  int l = threadIdx.x;
  float v = (l < 30) ? qa[(size_t)g * 30 + l] : -3.4e38f;
  float mx = waveMax(v);
  float e = (l < 30) ? expf(v - mx) : 0.f;
  float s = waveSum(e);
  if (l < 30) sim[(size_t)g * 30 + l] = e / s;
}

// ---------------------------------------------------------------------------
// Edge weights
// ---------------------------------------------------------------------------
__global__ __launch_bounds__(256) void edgew_kernel(const void* __restrict__ aaov,
                                                    const void* __restrict__ aasim_in,
                                                    const void* __restrict__ qaov,
                                                    const void* __restrict__ qq,
                                                    const float* __restrict__ aasm,
                                                    const float* __restrict__ sim,
                                                    const void* __restrict__ p1,
                                                    const void* __restrict__ p2,
                                                    const void* __restrict__ p3,
                                                    const void* __restrict__ p4,
                                                    float* __restrict__ Wout,
                                                    const int* __restrict__ F) {
  const int isb = *F;
  int e = blockIdx.x * 256 + threadIdx.x;
  if (e >= 16 * 1156) return;
  int b = e / 1156;
  int rem = e - b * 1156;
  int r = rem / 34, c = rem - r * 34;
  float aas;
  if (r >= 4 && c >= 4) aas = aasm[(size_t)b * 900 + (r - 4) * 30 + (c - 4)];
  else                  aas = ldf(aasim_in, e, isb);
  float qas = 0.f;
  if (r >= 4 && c < 4)      qas = sim[((size_t)b * 4 + c) * 30 + (r - 4)];
  else if (r < 4 && c >= 4) qas = sim[((size_t)b * 4 + r) * 30 + (c - 4)];
  float w = -ldf(p1, 0, isb) * ldf(aaov, e, isb) + ldf(p2, 0, isb) * aas +
            ldf(p3, 0, isb) * ldf(qaov, e, isb) + ldf(p4, 0, isb) * qas +
            ldf(qq, e, isb);
  Wout[e] = w;
}

// ---------------------------------------------------------------------------
// Projected gradient ascent (100 iters), register-resident, barrier-free.
// ---------------------------------------------------------------------------
__global__ __launch_bounds__(64) void solve_kernel(const float* __restrict__ Wmat,
                                                   float* __restrict__ pred,
                                                   float* __restrict__ outp) {
  const int b = blockIdx.x;
  const int lane = threadIdx.x;
  float E[19], Ws[19], As[19];
  bool dg[19];
#pragma unroll
  for (int k = 0; k < 19; k++) {
    int e = lane + (k << 6);
    if (e < 1156) {
      int r = e / 34, c = e - r * 34;
      float w1 = Wmat[(size_t)b * 1156 + e];
      float w2 = Wmat[(size_t)b * 1156 + c * 34 + r];
      Ws[k] = 0.5f * (w1 + w2);
      As[k] = 0.5f * (((w1 != 0.f) ? 1.f : 0.f) + ((w2 != 0.f) ? 1.f : 0.f));
      dg[k] = (r == c && r < 4);
      E[k] = 0.5f;
    } else {
      Ws[k] = 0.f; As[k] = 0.f; dg[k] = false; E[k] = 0.f;
    }
  }
  for (int it = 0; it < 100; it++) {
    float ps = 0.f;
#pragma unroll
    for (int k = 0; k < 19; k++) ps += As[k] * E[k];
    float s = waveSum(ps);
    float dd = __shfl(E[0], 0, 64) + __shfl(E[0], 35, 64) +
               __shfl(E[1], 6, 64) + __shfl(E[1], 41, 64);
    float coef_s = (s > 6.f) ? 20.f * (s - 6.f) : 0.f;
    float coef_d = 20.f * (dd - 1.f);
#pragma unroll
    for (int k = 0; k < 19; k++) {
      float g = Ws[k] - coef_s * As[k] - (dg[k] ? coef_d : 0.f);
      E[k] = fminf(fmaxf(E[k] + 0.05f * g, 0.f), 1.f);
    }
  }
  float v0 = E[0], v1 = E[1];
  if (lane == 0)  { pred[b * 4 + 0] = v0; outp[1 + b * 4 + 0] = v0; }
  if (lane == 35) { pred[b * 4 + 1] = v0; outp[1 + b * 4 + 1] = v0; }
  if (lane == 6)  { pred[b * 4 + 2] = v1; outp[1 + b * 4 + 2] = v1; }
  if (lane == 41) { pred[b * 4 + 3] = v1; outp[1 + b * 4 + 3] = v1; }
}

// ---------------------------------------------------------------------------
// Final loss: out[0] = ce(log_softmax(pred), labels) + mse(sim, gold_sm)
// ---------------------------------------------------------------------------
__global__ __launch_bounds__(256) void loss_kernel(const float* __restrict__ sim,
                                                   const void* __restrict__ gold,
                                                   const float* __restrict__ pred,
                                                   const int* __restrict__ labels,
                                                   float* __restrict__ outp,
                                                   const int* __restrict__ F) {
  const int isb = *F;
  __shared__ float sh[4];
  const int tid = threadIdx.x;
  float local = 0.f;
  if (tid < 64) {
    float mx = -3.4e38f;
    for (int k = 0; k < 30; k++) mx = fmaxf(mx, ldf(gold, (size_t)tid * 30 + k, isb));
    float sum = 0.f;
    for (int k = 0; k < 30; k++) sum += expf(ldf(gold, (size_t)tid * 30 + k, isb) - mx);
    float inv = 1.f / sum;
    for (int k = 0; k < 30; k++) {
      float gsm = expf(ldf(gold, (size_t)tid * 30 + k, isb) - mx) * inv;
      float d = sim[(size_t)tid * 30 + k] - gsm;
      local += d * d;
    }
  }
  float mse = blockSum(local, sh) * (1.f / 1920.f);
  float cel = 0.f;
  if (tid < 16) {
    const float* f = pred + tid * 4;
    int lb = labels[tid] & 3;
    float mx = fmaxf(fmaxf(f[0], f[1]), fmaxf(f[2], f[3]));
    float lse = logf(expf(f[0] - mx) + expf(f[1] - mx) + expf(f[2] - mx) + expf(f[3] - mx));
    float lp = f[lb] - mx - lse;
    cel = -lp * (1.f / 16.f);
  }
  float ce = blockSum(cel, sh);
  if (tid == 0) outp[0] = ce + mse;
}

// ---------------------------------------------------------------------------
// Host orchestration
// ---------------------------------------------------------------------------
extern "C" void kernel_launch(void* const* d_in, const int* in_sizes, int n_in,
                              void* d_out, int out_size, void* d_ws, size_t ws_size,
                              hipStream_t stream) {
  (void)in_sizes; (void)n_in; (void)out_size;
  const int*  hyp_ids   = (const int*)d_in[0];
  const void* hyp_mask  = d_in[1];
  const void* fact_mask = d_in[2];
  const int*  fact_ids  = (const int*)d_in[3];
  const void* aa_ov     = d_in[5];
  const void* aa_sim_in = d_in[6];
  const void* qa_ov     = d_in[8];
  const void* qq        = d_in[11];
  const int*  labels    = (const int*)d_in[12];
  const void* gold      = d_in[13];
  const void* emb       = d_in[14];
  const void* Wqkv      = d_in[15];
  const void* bqkv      = d_in[16];
  const void* Wo        = d_in[17];
  const void* bo        = d_in[18];
  const void* ln1g      = d_in[19];
  const void* ln1b      = d_in[20];
  const void* Wff1      = d_in[21];
  const void* bff1      = d_in[22];
  const void* Wff2      = d_in[23];
  const void* bff2      = d_in[24];
  const void* ln2g      = d_in[25];
  const void* ln2b      = d_in[26];
  const void* scoreW    = d_in[27];
  const void* scoreB    = d_in[28];
  const void* absW      = d_in[29];
  const void* absB      = d_in[30];
  const void* p_aaov    = d_in[31];
  const void* p_aasim   = d_in[32];
  const void* p_qaov    = d_in[33];
  const void* p_qasim   = d_in[34];
  float* out = (float*)d_out;

  char* ws = (char*)d_ws;
  size_t off = 0;
  auto alloc = [&](size_t bytes) -> void* {
    void* p = ws + off;
    off += (bytes + 255) & ~(size_t)255;
    return p;
  };

  float* PRED = (float*)alloc(64ull * 4);
  int*   FLAG = (int*)alloc(256);
  float* SIM  = (float*)alloc(16ull * 120 * 4);
  float* QA   = (float*)alloc(16ull * 120 * 4);
  float* AASM = (float*)alloc(16ull * 900 * 4);
  float* AA   = (float*)alloc(16ull * 900 * 4);
  float* WMAT = (float*)alloc(16ull * 1156 * 4);
  float* FSEQ = (float*)alloc(480ull * 512 * 4);
  float* HSEQ = (float*)alloc(64ull * 512 * 4);
  u16* WT_QKV = (u16*)alloc(2ull * 1536 * 512 * 2);
  u16* WT_O   = (u16*)alloc(2ull * 512 * 512 * 2);
  u16* WT_F1  = (u16*)alloc(2ull * 2048 * 512 * 2);
  u16* WT_F2  = (u16*)alloc(2ull * 512 * 2048 * 2);

  // Dynamic chunking from ws_size (constant per process -> graph-safe).
  const int opts_tok[5] = {30720, 15360, 10240, 6144, 3072};
  const int opts_nch[5] = {1, 2, 3, 5, 10};
  int CH_TOK = 3072, NCH = 10;
  for (int i = 0; i < 5; i++) {
    size_t need = off + (size_t)opts_tok[i] * 7168 + 4096;
    if (need <= ws_size) { CH_TOK = opts_tok[i]; NCH = opts_nch[i]; break; }
  }
  u16* X   = (u16*)alloc((size_t)CH_TOK * 512 * 2);
  u16* BIG = (u16*)alloc((size_t)CH_TOK * 2048 * 2);
  u16* ATT = (u16*)alloc((size_t)CH_TOK * 512 * 2);
  u16* Y   = (u16*)alloc((size_t)CH_TOK * 512 * 2);

  detect_kernel<<<1, 1, 0, stream>>>(ln1g, FLAG);

  for (int l = 0; l < 2; l++) {
    transpose_kernel<<<dim3(48, 16), 256, 0, stream>>>(
        Wqkv, WT_QKV + (size_t)l * 1536 * 512, 512, 1536, (size_t)l * 512 * 1536, FLAG);
    transpose_kernel<<<dim3(16, 16), 256, 0, stream>>>(
        Wo, WT_O + (size_t)l * 512 * 512, 512, 512, (size_t)l * 512 * 512, FLAG);
    transpose_kernel<<<dim3(64, 16), 256, 0, stream>>>(
        Wff1, WT_F1 + (size_t)l * 2048 * 512, 512, 2048, (size_t)l * 512 * 2048, FLAG);
    transpose_kernel<<<dim3(16, 64), 256, 0, stream>>>(
        Wff2, WT_F2 + (size_t)l * 512 * 2048, 2048, 512, (size_t)l * 2048 * 512, FLAG);
  }

  auto encode = [&](const int* ids, int nseq, int L, const void* mask,
                    size_t moff, float* pooled) {
    int M = nseq * L;   // multiple of 128
    embed_kernel<<<M, 256, 0, stream>>>(ids, emb, X, L, FLAG);
    for (int l = 0; l < 2; l++) {
      gemm_bt<0><<<dim3(12, M / 128), 256, 0, stream>>>(
          X, WT_QKV + (size_t)l * 1536 * 512, bqkv, BIG, M, 1536, 512,
          (size_t)l * 1536, FLAG);
      attn_kernel<<<nseq * 8, 256, 0, stream>>>(BIG, ATT, L);
      gemm_bt<0><<<dim3(4, M / 128), 256, 0, stream>>>(
          ATT, WT_O + (size_t)l * 512 * 512, bo, Y, M, 512, 512,
          (size_t)l * 512, FLAG);
      add_ln_kernel<<<M, 256, 0, stream>>>(X, Y, ln1g, ln1b, (size_t)l * 512, FLAG);
      gemm_bt<1><<<dim3(16, M / 128), 256, 0, stream>>>(
          X, WT_F1 + (size_t)l * 2048 * 512, bff1, BIG, M, 2048, 512,
          (size_t)l * 2048, FLAG);
      gemm_bt<0><<<dim3(4, M / 128), 256, 0, stream>>>(
          BIG, WT_F2 + (size_t)l * 512 * 2048, bff2, Y, M, 512, 2048,
          (size_t)l * 512, FLAG);
      add_ln_kernel<<<M, 256, 0, stream>>>(X, Y, ln2g, ln2b, (size_t)l * 512, FLAG);
    }
    pool_kernel<<<nseq, 256, 0, stream>>>(X, mask, pooled, L, moff, FLAG);
  };

  const int seq_per = 480 / NCH;
  for (int c = 0; c < NCH; c++) {
    encode(fact_ids + (size_t)c * seq_per * 64, seq_per, 64, fact_mask,
           (size_t)c * seq_per * 64, FSEQ + (size_t)c * seq_per * 512);
  }
  encode(hyp_ids, 64, 32, hyp_mask, 0, HSEQ);

  pair_score_kernel<<<16 * 30 * 30, 64, 0, stream>>>(FSEQ, FSEQ, absW, absB, AA, 30, 30, FLAG);
  pair_score_kernel<<<16 * 4 * 30, 64, 0, stream>>>(HSEQ, FSEQ, scoreW, scoreB, QA, 4, 30, FLAG);
  aa_softmax_kernel<<<16, 256, 0, stream>>>(AA, AASM);
  qa_softmax_kernel<<<64, 64, 0, stream>>>(QA, SIM);

  edgew_kernel<<<(16 * 1156 + 255) / 256, 256, 0, stream>>>(
      aa_ov, aa_sim_in, qa_ov, qq, AASM, SIM, p_aaov, p_aasim, p_qaov, p_qasim,
      WMAT, FLAG);
  solve_kernel<<<16, 64, 0, stream>>>(WMAT, PRED, out);
  loss_kernel<<<1, 256, 0, stream>>>(SIM, gold, PRED, labels, out, FLAG);
}